// Round 6
// baseline (1008.761 us; speedup 1.0000x reference)
//
#include <hip/hip_runtime.h>
#include <stdint.h>

// ---------------------------------------------------------------------------
// SparseDiffAttention R5: dense MFMA flash (32-rows/wave, reg-prefetch
// pipeline) + 2-slot colsum -> select (coarse radix + exact fp32 window +
// threefry random) -> sparse MFMA flash (gathered K, quad-packed V transpose)
// -> out = stack([o, o - spo]).
// ---------------------------------------------------------------------------

#define JAX_PARTITIONABLE 1

namespace {
constexpr int H   = 16;
constexpr int N   = 3072;
constexpr int Dh  = 128;
constexpr int M   = 16;
constexpr int TK  = 64;
constexpr int NT  = N / TK;        // 48
constexpr float SCALE = 0.08838834764831845f;
constexpr size_t HEAD_STRIDE = (size_t)N * Dh;
constexpr size_t OUT_HALF    = (size_t)H * N * Dh;

constexpr int IDXCAP = 1024;
constexpr int CAND_MAX = 128;

// dense kernel geometry
constexpr int BQD = 128;
constexpr int NBD = N / BQD;       // 24 blocks/head
// dense LDS (bytes)
constexpr int D_KH  = 0;           // 64x128 bf16 swz (16384)
constexpr int D_KL  = 16384;
constexpr int D_VT  = 32768;       // 128d x 64c bf16 swz (16384)
constexpr int D_PB  = 49152;       // 4 waves x 32q x 64c bf16 swz (16384)
constexpr int D_CSR = 65536;       // 4 x 64 f32
constexpr int DENSE_SM = 66560;

// sparse kernel geometry (64 q-rows, 4 waves x 16 rows) — proven R4 structure
constexpr int BQ  = 64;
constexpr int NQB = N / BQ;        // 48
constexpr int SP_KH  = 0;
constexpr int SP_KL  = 16384;
constexpr int SP_VT  = 32768;      // [128 d][72 shorts] (144B rows)
constexpr int SP_PB  = 51200;
constexpr int SP_IDX = 59392;
constexpr int SPMF_SM = 59648;

// ws layout (bytes)
constexpr size_t CS_B   = 0;                        // [H][24][2][N] f32 = 9.44MB
constexpr size_t IDX_B  = 9437184;                  // [H][M][IDXCAP] i32
constexpr size_t NSEL_B = IDX_B + (size_t)H*M*IDXCAP*4;
constexpr size_t KH_B   = NSEL_B + 1024;
constexpr size_t KL_B   = KH_B + 12582912;
constexpr size_t NEED_B = KL_B + 12582912;          // 35.7MB (ws proven >= 44MB)
}

typedef float f4v __attribute__((ext_vector_type(4)));
typedef short s8v __attribute__((ext_vector_type(8)));

__device__ __forceinline__ unsigned short f2bf(float x) {
  unsigned u = __float_as_uint(x);
  unsigned r = u + 0x7FFFu + ((u >> 16) & 1u);
  return (unsigned short)(r >> 16);
}
__device__ __forceinline__ float bf2f(unsigned short b) {
  return __uint_as_float(((unsigned)b) << 16);
}

// ------------------------------ threefry -----------------------------------
__device__ __forceinline__ void tf_round(uint32_t& x0, uint32_t& x1, int r) {
  x0 += x1; x1 = (x1 << r) | (x1 >> (32 - r)); x1 ^= x0;
}
__device__ __forceinline__ void tf2x32(uint32_t k0, uint32_t k1,
                                       uint32_t x0, uint32_t x1,
                                       uint32_t& y0, uint32_t& y1) {
  uint32_t k2 = k0 ^ k1 ^ 0x1BD11BDAu;
  x0 += k0; x1 += k1;
  tf_round(x0,x1,13); tf_round(x0,x1,15); tf_round(x0,x1,26); tf_round(x0,x1,6);
  x0 += k1; x1 += k2 + 1u;
  tf_round(x0,x1,17); tf_round(x0,x1,29); tf_round(x0,x1,16); tf_round(x0,x1,24);
  x0 += k2; x1 += k0 + 2u;
  tf_round(x0,x1,13); tf_round(x0,x1,15); tf_round(x0,x1,26); tf_round(x0,x1,6);
  x0 += k0; x1 += k1 + 3u;
  tf_round(x0,x1,17); tf_round(x0,x1,29); tf_round(x0,x1,16); tf_round(x0,x1,24);
  x0 += k1; x1 += k2 + 4u;
  tf_round(x0,x1,13); tf_round(x0,x1,15); tf_round(x0,x1,26); tf_round(x0,x1,6);
  x0 += k2; x1 += k0 + 5u;
  y0 = x0; y1 = x1;
}

__device__ __forceinline__ bool jax_rand_zero(uint32_t idx) {
  uint32_t hi, lo, r0, r1;
#if JAX_PARTITIONABLE
  uint32_t a0,a1,b0,b1;
  tf2x32(0u,42u, 0u,0u, a0,a1);
  tf2x32(0u,42u, 0u,1u, b0,b1);
  tf2x32(a0,a1, 0u, idx, r0,r1);  hi = r0 ^ r1;
  tf2x32(b0,b1, 0u, idx, r0,r1);  lo = r0 ^ r1;
#else
  uint32_t p0x,p0y,p1x,p1y;
  tf2x32(0u,42u, 0u,2u, p0x,p0y);
  tf2x32(0u,42u, 1u,3u, p1x,p1y);
  const uint32_t half = (uint32_t)((size_t)H*M*N) / 2u;
  uint32_t i = (idx < half) ? idx : (idx - half);
  uint32_t h0,h1,l0,l1;
  tf2x32(p0x, p1x, i, i + half, h0, h1);
  tf2x32(p0y, p1y, i, i + half, l0, l1);
  hi = (idx < half) ? h0 : h1;
  lo = (idx < half) ? l0 : l1;
#endif
  uint32_t off = ((hi % 100u) * 96u + (lo % 100u)) % 100u;
  return off == 0u;
}

// ----------------------- precompute: K -> Kh,Kl bf16 ------------------------
__global__ __launch_bounds__(256) void split_bf16_kernel(
    const float* __restrict__ K, unsigned short* __restrict__ Kh,
    unsigned short* __restrict__ Kl)
{
  size_t i = ((size_t)blockIdx.x * 256 + threadIdx.x) * 4;
  float4 v = *(const float4*)(K + i);
  unsigned short h0 = f2bf(v.x), h1 = f2bf(v.y), h2 = f2bf(v.z), h3 = f2bf(v.w);
  unsigned short l0 = f2bf(v.x - bf2f(h0)), l1 = f2bf(v.y - bf2f(h1));
  unsigned short l2 = f2bf(v.z - bf2f(h2)), l3 = f2bf(v.w - bf2f(h3));
  uint2 hu, lu;
  hu.x = (unsigned)h0 | ((unsigned)h1 << 16); hu.y = (unsigned)h2 | ((unsigned)h3 << 16);
  lu.x = (unsigned)l0 | ((unsigned)l1 << 16); lu.y = (unsigned)l2 | ((unsigned)l3 << 16);
  *(uint2*)(Kh + i) = hu;
  *(uint2*)(Kl + i) = lu;
}

// ----------------------- precompute: V -> Vt bf16 [H][Dh][N] ----------------
__global__ __launch_bounds__(256) void transpose_v_kernel(
    const float* __restrict__ Vm, unsigned short* __restrict__ Vt)
{
  __shared__ unsigned short tb[64][132];
  const int h  = blockIdx.x;
  const int cb = blockIdx.y;
  const int tid = threadIdx.x;
  const float* vg = Vm + (size_t)h*HEAD_STRIDE + (size_t)(cb*64)*Dh;
  #pragma unroll
  for (int it = 0; it < 8; ++it) {
    int f = tid + 256*it;
    int c = f >> 5, d0 = (f & 31)*4;
    float4 v = *(const float4*)(vg + c*Dh + d0);
    tb[c][d0+0] = f2bf(v.x); tb[c][d0+1] = f2bf(v.y);
    tb[c][d0+2] = f2bf(v.z); tb[c][d0+3] = f2bf(v.w);
  }
  __syncthreads();
  unsigned short* vt = Vt + (size_t)h*((size_t)Dh*N) + (size_t)(cb*64);
  #pragma unroll
  for (int it = 0; it < 4; ++it) {
    int f = tid + 256*it;
    int d = f >> 3, sl = f & 7;
    union { unsigned short us[8]; uint4 u; } o;
    #pragma unroll
    for (int i = 0; i < 8; ++i) o.us[i] = tb[sl*8 + i][d];
    *(uint4*)(vt + (size_t)d*N + sl*8) = o.u;
  }
}

// ------------------ dense MFMA flash: 4 waves x 32 rows ---------------------
__global__ __launch_bounds__(256, 2) void dense_mfma2_kernel(
    const float* __restrict__ Qm, const unsigned short* __restrict__ Khg,
    const unsigned short* __restrict__ Klg, const unsigned short* __restrict__ Vtg,
    const float* __restrict__ PL, float* __restrict__ Out,
    float* __restrict__ csPart)
{
  extern __shared__ char smc[];
  char* KH = smc + D_KH;
  char* KL = smc + D_KL;
  char* VT = smc + D_VT;
  char* PB = smc + D_PB;
  float* CSR = (float*)(smc + D_CSR);

  const int id  = blockIdx.x;
  const int wid = (id & 7) * 48 + (id >> 3);   // 384 blocks, XCD-chunked
  const int h   = wid / NBD;
  const int qb  = wid % NBD;
  const int q0  = qb * BQD;
  const int bmod = qb % 3;

  const int tid = threadIdx.x;
  const int wv  = tid >> 6;
  const int ln  = tid & 63;
  const int g   = ln >> 4;
  const int l15 = ln & 15;
  const size_t hqk = (size_t)h * HEAD_STRIDE;

  // ---- Q fragments: global -> reg, in-reg hi/lo split ----
  s8v qh[2][4], ql[2][4];
  #pragma unroll
  for (int s = 0; s < 2; ++s) {
    const float* qrp = Qm + hqk + (size_t)(q0 + 32*wv + 16*s + l15) * Dh;
    #pragma unroll
    for (int k0i = 0; k0i < 4; ++k0i) {
      int d0 = (4*k0i + g) * 8;
      float4 a = *(const float4*)(qrp + d0);
      float4 b = *(const float4*)(qrp + d0 + 4);
      float vals[8] = {a.x,a.y,a.z,a.w,b.x,b.y,b.z,b.w};
      union { unsigned short u[8]; s8v s; } hh, lo;
      #pragma unroll
      for (int j = 0; j < 8; ++j) {
        float x = vals[j] * SCALE;
        unsigned short hb = f2bf(x);
        hh.u[j] = hb;
        lo.u[j] = f2bf(x - bf2f(hb));
      }
      qh[s][k0i] = hh.s; ql[s][k0i] = lo.s;
    }
  }

  float mo[2][4], ll[2][4], plr[2][4];
  #pragma unroll
  for (int s = 0; s < 2; ++s)
    #pragma unroll
    for (int r = 0; r < 4; ++r) {
      mo[s][r] = -1e30f; ll[s][r] = 0.0f;
      plr[s][r] = PL[(size_t)h*N + q0 + 32*wv + 16*s + 4*g + r];
    }
  f4v oac[2][8];
  #pragma unroll
  for (int s = 0; s < 2; ++s)
    #pragma unroll
    for (int t = 0; t < 8; ++t) oac[s][t] = (f4v){0.f,0.f,0.f,0.f};

  const unsigned kswz = ((unsigned)(l15 & 7)) << 4;
  const unsigned vkey = kswz;
  const unsigned pkey = ((unsigned)((l15 >> 1) & 7)) << 4;

  // ---- prologue: stage tile 0 synchronously ----
  {
    const unsigned short* khg = Khg + hqk;
    const unsigned short* klg = Klg + hqk;
    const unsigned short* vtg = Vtg + (size_t)h*((size_t)Dh*N);
    #pragma unroll
    for (int i = 0; i < 8; ++i) {
      int f = tid + 256*i;
      int pl = f >> 10, e = f & 1023, row = e >> 4, sl = e & 15;
      uint4 v = *(const uint4*)((pl ? klg : khg) + row*Dh + sl*8);
      unsigned off = (unsigned)(row*256) + (((unsigned)(sl*16)) ^ ((unsigned)(row&7) << 4));
      *(uint4*)((pl ? KL : KH) + off) = v;
    }
    #pragma unroll
    for (int i = 0; i < 4; ++i) {
      int e = tid + 256*i;
      int d = e >> 3, sl = e & 7;
      uint4 v = *(const uint4*)(vtg + (size_t)d*N + sl*8);
      unsigned off = (unsigned)(d*128) + (((unsigned)(sl*16)) ^ ((unsigned)(d&7) << 4));
      *(uint4*)(VT + off) = v;
    }
  }
  __syncthreads();

  uint4 kpf[8], vpf[4];
  for (int kt = 0; kt < NT; ++kt) {
    const bool pf = (kt + 1 < NT);
    // ---- phase A: prefetch K(t+1), QK, softmax, PB+CSR write ----
    if (pf) {
      const unsigned short* khg = Khg + hqk + (size_t)((kt+1)*TK)*Dh;
      const unsigned short* klg = Klg + hqk + (size_t)((kt+1)*TK)*Dh;
      #pragma unroll
      for (int i = 0; i < 8; ++i) {
        int f = tid + 256*i;
        int pl = f >> 10, e = f & 1023, row = e >> 4, sl = e & 15;
        kpf[i] = *(const uint4*)((pl ? klg : khg) + row*Dh + sl*8);
      }
    }

    f4v S0[4], S1[4];
    #pragma unroll
    for (int t = 0; t < 4; ++t) { S0[t] = (f4v){0.f,0.f,0.f,0.f}; S1[t] = (f4v){0.f,0.f,0.f,0.f}; }
    #pragma unroll
    for (int k0i = 0; k0i < 4; ++k0i) {
      #pragma unroll
      for (int t = 0; t < 4; ++t) {
        unsigned off = (unsigned)(t*4096 + l15*256) + (((unsigned)((k0i*4 + g)*16)) ^ kswz);
        union { uint4 u; s8v s; } kh_, kl_;
        kh_.u = *(const uint4*)(KH + off);
        kl_.u = *(const uint4*)(KL + off);
        S0[t] = __builtin_amdgcn_mfma_f32_16x16x32_bf16(qh[0][k0i], kh_.s, S0[t], 0, 0, 0);
        S1[t] = __builtin_amdgcn_mfma_f32_16x16x32_bf16(qh[1][k0i], kh_.s, S1[t], 0, 0, 0);
        S0[t] = __builtin_amdgcn_mfma_f32_16x16x32_bf16(qh[0][k0i], kl_.s, S0[t], 0, 0, 0);
        S1[t] = __builtin_amdgcn_mfma_f32_16x16x32_bf16(qh[1][k0i], kl_.s, S1[t], 0, 0, 0);
        S0[t] = __builtin_amdgcn_mfma_f32_16x16x32_bf16(ql[0][k0i], kh_.s, S0[t], 0, 0, 0);
        S1[t] = __builtin_amdgcn_mfma_f32_16x16x32_bf16(ql[1][k0i], kh_.s, S1[t], 0, 0, 0);
      }
    }

    float sc[2][4], wq[2][4], p[2][4][4];
    #pragma unroll
    for (int s = 0; s < 2; ++s) {
      f4v* S = s ? S1 : S0;
      #pragma unroll
      for (int r = 0; r < 4; ++r) {
        float v = fmaxf(fmaxf(S[0][r], S[1][r]), fmaxf(S[2][r], S[3][r]));
        v = fmaxf(v, __shfl_xor(v, 1)); v = fmaxf(v, __shfl_xor(v, 2));
        v = fmaxf(v, __shfl_xor(v, 4)); v = fmaxf(v, __shfl_xor(v, 8));
        float mn = fmaxf(mo[s][r], v);
        sc[s][r] = __expf(mo[s][r] - mn);
        wq[s][r] = __expf(mn - plr[s][r]);
        mo[s][r] = mn;
      }
      #pragma unroll
      for (int r = 0; r < 4; ++r) {
        float rs = 0.f;
        #pragma unroll
        for (int t = 0; t < 4; ++t) {
          float pv = __expf(S[t][r] - mo[s][r]);
          p[s][t][r] = pv; rs += pv;
        }
        rs += __shfl_xor(rs, 1); rs += __shfl_xor(rs, 2);
        rs += __shfl_xor(rs, 4); rs += __shfl_xor(rs, 8);
        ll[s][r] = ll[s][r]*sc[s][r] + rs;
      }
    }
    // colsum partials: sum over this wave's 32 rows
    #pragma unroll
    for (int t = 0; t < 4; ++t) {
      float cv = 0.f;
      #pragma unroll
      for (int s = 0; s < 2; ++s)
        #pragma unroll
        for (int r = 0; r < 4; ++r) cv += p[s][t][r] * wq[s][r];
      cv += __shfl_xor(cv, 16); cv += __shfl_xor(cv, 32);
      if (ln < 16) CSR[wv*64 + 16*t + ln] = cv;
    }
    // rescale O
    #pragma unroll
    for (int s = 0; s < 2; ++s)
      #pragma unroll
      for (int t = 0; t < 8; ++t) {
        f4v o = oac[s][t];
        o[0] *= sc[s][0]; o[1] *= sc[s][1]; o[2] *= sc[s][2]; o[3] *= sc[s][3];
        oac[s][t] = o;
      }
    // write P~ bf16 (swizzled), PB row = 16s+4g+r within wave's 32
    #pragma unroll
    for (int s = 0; s < 2; ++s)
      #pragma unroll
      for (int r = 0; r < 4; ++r) {
        int qlr = 16*s + 4*g + r;
        unsigned key = ((unsigned)((qlr >> 1) & 7)) << 4;
        char* rowp = PB + wv*4096 + qlr*128;
        #pragma unroll
        for (int t = 0; t < 4; ++t) {
          unsigned off = ((unsigned)(32*t + 2*l15)) ^ key;
          *(unsigned short*)(rowp + off) = f2bf(p[s][t][r]);
        }
      }
    __syncthreads();   // #1

    // ---- phase B: colsum -> global (2 slots), prefetch VT(t+1), PV ----
    if (tid < 64) {
      size_t cbase = ((size_t)(h*NBD + qb)*2)*N + kt*TK + tid;
      if (bmod == 1) {
        csPart[cbase]     = CSR[tid] + CSR[64 + tid];
        csPart[cbase + N] = CSR[128 + tid] + CSR[192 + tid];
      } else {
        csPart[cbase] = (CSR[tid] + CSR[64 + tid]) + (CSR[128 + tid] + CSR[192 + tid]);
      }
    }
    if (pf) {
      const unsigned short* vtg = Vtg + (size_t)h*((size_t)Dh*N) + (size_t)((kt+1)*TK);
      #pragma unroll
      for (int i = 0; i < 4; ++i) {
        int e = tid + 256*i;
        int d = e >> 3, sl = e & 7;
        vpf[i] = *(const uint4*)(vtg + (size_t)d*N + sl*8);
      }
    }
    {
      s8v pa0[2], pa1[2];
      #pragma unroll
      for (int s = 0; s < 2; ++s) {
        const char* prow = PB + wv*4096 + (16*s + l15)*128;
        union { uint4 u; s8v v; } a, b;
        a.u = *(const uint4*)(prow + (((unsigned)(16*g)) ^ pkey));
        b.u = *(const uint4*)(prow + (((unsigned)(64 + 16*g)) ^ pkey));
        pa0[s] = a.v; pa1[s] = b.v;
      }
      #pragma unroll
      for (int t = 0; t < 8; ++t) {
        const char* vrow = VT + (16*t + l15)*128;
        union { uint4 u; s8v v; } b0, b1;
        b0.u = *(const uint4*)(vrow + (((unsigned)(16*g)) ^ vkey));
        b1.u = *(const uint4*)(vrow + (((unsigned)(64 + 16*g)) ^ vkey));
        oac[0][t] = __builtin_amdgcn_mfma_f32_16x16x32_bf16(pa0[0], b0.v, oac[0][t], 0, 0, 0);
        oac[1][t] = __builtin_amdgcn_mfma_f32_16x16x32_bf16(pa0[1], b0.v, oac[1][t], 0, 0, 0);
        oac[0][t] = __builtin_amdgcn_mfma_f32_16x16x32_bf16(pa1[0], b1.v, oac[0][t], 0, 0, 0);
        oac[1][t] = __builtin_amdgcn_mfma_f32_16x16x32_bf16(pa1[1], b1.v, oac[1][t], 0, 0, 0);
      }
    }
    __syncthreads();   // #2

    // ---- phase C: write staged regs to LDS ----
    if (pf) {
      #pragma unroll
      for (int i = 0; i < 8; ++i) {
        int f = tid + 256*i;
        int pl = f >> 10, e = f & 1023, row = e >> 4, sl = e & 15;
        unsigned off = (unsigned)(row*256) + (((unsigned)(sl*16)) ^ ((unsigned)(row&7) << 4));
        *(uint4*)((pl ? KL : KH) + off) = kpf[i];
      }
      #pragma unroll
      for (int i = 0; i < 4; ++i) {
        int e = tid + 256*i;
        int d = e >> 3, sl = e & 7;
        unsigned off = (unsigned)(d*128) + (((unsigned)(sl*16)) ^ ((unsigned)(d&7) << 4));
        *(uint4*)(VT + off) = vpf[i];
      }
    }
    __syncthreads();   // #3
  }

  // ---- epilogue ----
  #pragma unroll
  for (int s = 0; s < 2; ++s) {
    float inv[4];
    #pragma unroll
    for (int r = 0; r < 4; ++r) inv[r] = 1.0f / ll[s][r];
    #pragma unroll
    for (int t = 0; t < 8; ++t)
      #pragma unroll
      for (int r = 0; r < 4; ++r) {
        int row = q0 + 32*wv + 16*s + 4*g + r;
        Out[hqk + (size_t)row*Dh + 16*t + l15] = oac[s][t][r] * inv[r];
      }
  }
}

// --------------------- sparse MFMA flash + out_cache ------------------------
__global__ __launch_bounds__(256, 2) void sparse_mfma_kernel(
    const float* __restrict__ Qm, const unsigned short* __restrict__ Khg,
    const unsigned short* __restrict__ Klg, const float* __restrict__ Vm,
    const int* __restrict__ idxList, const int* __restrict__ nSel,
    float* __restrict__ Out)
{
  extern __shared__ char smc[];
  char* KH = smc + SP_KH;
  char* KL = smc + SP_KL;
  unsigned short* VTs = (unsigned short*)(smc + SP_VT);   // [128][72]
  char* PB = smc + SP_PB;
  int* idxs = (int*)(smc + SP_IDX);

  const int id  = blockIdx.x;
  const int wid = (id & 7) * 96 + (id >> 3);
  const int h   = wid / NQB;
  const int qb  = wid % NQB;
  const int gq  = qb / 3;
  const int q0  = qb * BQ;

  const int tid = threadIdx.x;
  const int wv  = tid >> 6;
  const int ln  = tid & 63;
  const int g   = ln >> 4;
  const int l15 = ln & 15;

  const size_t hqk = (size_t)h * HEAD_STRIDE;

  // ---- stage Q (scaled, split hi/lo) into KH/KL; load frags ----
  {
    const float* qg = Qm + hqk + (size_t)q0 * Dh;
    #pragma unroll
    for (int it = 0; it < 8; ++it) {
      int f = tid + 256*it;
      int row = f >> 5, d0 = (f & 31) * 4;
      float4 v = *(const float4*)(qg + row*Dh + d0);
      v.x *= SCALE; v.y *= SCALE; v.z *= SCALE; v.w *= SCALE;
      unsigned short h0 = f2bf(v.x), h1 = f2bf(v.y), h2 = f2bf(v.z), h3 = f2bf(v.w);
      unsigned short o0 = f2bf(v.x - bf2f(h0)), o1 = f2bf(v.y - bf2f(h1));
      unsigned short o2 = f2bf(v.z - bf2f(h2)), o3 = f2bf(v.w - bf2f(h3));
      unsigned off = (unsigned)(row*256) + (((unsigned)(d0*2)) ^ ((unsigned)(row&7) << 4));
      uint2 hu, lu;
      hu.x = (unsigned)h0 | ((unsigned)h1<<16); hu.y = (unsigned)h2 | ((unsigned)h3<<16);
      lu.x = (unsigned)o0 | ((unsigned)o1<<16); lu.y = (unsigned)o2 | ((unsigned)o3<<16);
      *(uint2*)(KH + off) = hu;
      *(uint2*)(KL + off) = lu;
    }
  }
  __syncthreads();
  s8v qh[4], qlo[4];
  {
    const int qrow = 16*wv + l15;
    const unsigned qswz = ((unsigned)(qrow & 7)) << 4;
    #pragma unroll
    for (int k0i = 0; k0i < 4; ++k0i) {
      unsigned off = (unsigned)(qrow*256) + (((unsigned)((k0i*4 + g)*16)) ^ qswz);
      union { uint4 u; s8v s; } a, b;
      a.u = *(const uint4*)(KH + off);
      b.u = *(const uint4*)(KL + off);
      qh[k0i] = a.s; qlo[k0i] = b.s;
    }
  }

  float mo[4], ll[4];
  #pragma unroll
  for (int r = 0; r < 4; ++r) { mo[r] = -1e30f; ll[r] = 0.0f; }
  f4v oacc[8];
  #pragma unroll
  for (int t = 0; t < 8; ++t) oacc[t] = (f4v){0.f, 0.f, 0.f, 0.f};

  const unsigned kswz = ((unsigned)(l15 & 7)) << 4;

  int nsel = nSel[h*M + gq];
  if (nsel > IDXCAP) nsel = IDXCAP;
  const int* il = idxList + ((size_t)h*M + gq) * IDXCAP;
  const int nt = (nsel + TK - 1) / TK;

  for (int t = 0; t < nt; ++t) {
    const int cnt = min(TK, nsel - t*TK);
    __syncthreads();
    if (tid < 64) idxs[tid] = (tid < cnt) ? il[t*TK + tid] : 0;
    __syncthreads();

    // ---- gather-stage K (split bf16 rows, b128 swz writes) ----
    {
      const int row = tid & 63;
      const int c = idxs[row];
      const unsigned short* khr = Khg + hqk + (size_t)c * Dh;
      const unsigned short* klr = Klg + hqk + (size_t)c * Dh;
      const unsigned swz = ((unsigned)(row & 7)) << 4;
      #pragma unroll
      for (int j = 0; j < 4; ++j) {
        int chunk = (tid >> 6) + 4*j;
        unsigned off = (unsigned)(row*256) + (((unsigned)(chunk*16)) ^ swz);
        *(uint4*)(KH + off) = *(const uint4*)(khr + chunk*8);
        *(uint4*)(KL + off) = *(const uint4*)(klr + chunk*8);
      }
      // ---- gather-stage V: quad-packed transpose (4 cols x 8 d per thread) --
      const int q4 = tid & 15;          // col-quad
      const int seg = tid >> 4;         // d-rows 8*seg..+7
      int c4[4];
      #pragma unroll
      for (int j = 0; j < 4; ++j) c4[j] = idxs[4*q4 + j];
      union { float4 f4[2]; float f[8]; } col[4];
      #pragma unroll
      for (int j = 0; j < 4; ++j) {
        const float* vr = Vm + hqk + (size_t)c4[j]*Dh + 8*seg;
        col[j].f4[0] = *(const float4*)(vr);
        col[j].f4[1] = *(const float4*)(vr + 4);
      }
      #pragma unroll
      for (int dd = 0; dd < 8; ++dd) {
        unsigned short b0 = f2bf(col[0].f[dd]), b1 = f2bf(col[1].f[dd]);
        unsigned short b2 = f2bf(col[2].f[dd]), b3 = f2bf(col[3].f[dd]);
        uint2 pk;
        pk.x = (unsigned)b0 | ((unsigned)b1 << 16);
        pk.y = (unsigned)b2 | ((unsigned)b3 << 16);
        *(uint2*)((char*)VTs + (8*seg + dd)*144 + q4*8) = pk;
      }
    }
    __syncthreads();

    // ---- QK^T: 3-product split-bf16 MFMA ----
    f4v S[4];
    #pragma unroll
    for (int u = 0; u < 4; ++u) S[u] = (f4v){0.f, 0.f, 0.f, 0.f};
    #pragma unroll
    for (int k0i = 0; k0i < 4; ++k0i) {
      #pragma unroll
      for (int u = 0; u < 4; ++u) {
        unsigned off = (unsigned)(u*4096 + l15*256) + (((unsigned)((k0i*4 + g)*16)) ^ kswz);
        union { uint4 u4; s8v s; } kh_, kl_;
        kh_.u4 = *(const uint4*)(KH + off);
        kl_.u4 = *(const uint4*)(KL + off);
        S[u] = __builtin_amdgcn_mfma_f32_16x16x32_bf16(qh[k0i], kh_.s, S[u], 0, 0, 0);
        S[u] = __builtin_amdgcn_mfma_f32_16x16x32_bf16(qh[k0i], kl_.s, S[u], 0, 0, 0);
        S[u] = __builtin_amdgcn_mfma_f32_16x16x32_bf16(qlo[k0i], kh_.s, S[u], 0, 0, 0);
      }
    }
    #pragma unroll
    for (int u = 0; u < 4; ++u)
      if (16*u + l15 >= cnt) S[u] = (f4v){-1e30f, -1e30f, -1e30f, -1e30f};

    // ---- online softmax ----
    float sc[4], p[4][4];
    #pragma unroll
    for (int r = 0; r < 4; ++r) {
      float v = fmaxf(fmaxf(S[0][r], S[1][r]), fmaxf(S[2][r], S[3][r]));
      v = fmaxf(v, __shfl_xor(v, 1)); v = fmaxf(v, __shfl_xor(v, 2));
      v = fmaxf(v, __shfl_xor(v, 4)); v = fmaxf(v, __shfl_xor(v, 8));
      float mn = fmaxf(mo[r], v);
      sc[r] = __expf(mo[r] - mn);
      mo[r] = mn;
    }
    #pragma unroll
    for (int r = 0; r < 4; ++r) {
      float rs = 0.f;
      #pragma unroll
      for (int u = 0; u < 4; ++u) { float pv = __expf(S[u][r] - mo[r]); p[u][r] = pv; rs += pv; }
      rs += __shfl_xor(rs, 1); rs += __shfl_xor(rs, 2);
      rs += __shfl_xor(rs, 4); rs += __shfl_xor(rs, 8);
      ll[r] = ll[r]*sc[r] + rs;
    }
    #pragma unroll
    for (int u = 0; u < 8; ++u) {
      f4v o = oacc[u];
      o[0] *= sc[0]; o[1] *= sc[1]; o[2] *= sc[2]; o[3] *= sc[3];
      oacc[u] = o;
    }
    #pragma unroll
    for (int r = 0; r < 4; ++r) {
      int qlr = 4*g + r;
      unsigned key = ((unsigned)((qlr >> 1) & 7)) << 4;
      char* rowp = PB + wv*2048 + qlr*128;
      #pragma unroll
      for (int u = 0; u < 4; ++u) {
        unsigned off = ((unsigned)(32*u + 2*l15)) ^ key;
        *(unsigned short*)(rowp + off) = f2bf(p[u][r]);
      }
    }
    __syncthreads();

    // ---- PV ----
    {
      const unsigned pkey = ((unsigned)((l15 >> 1) & 7)) << 4;
      const char* prow = PB + wv*2048 + l15*128;
      union { uint4 u4; s8v s; } pa0u, pa1u;
      pa0u.u4 = *(const uint4*)(prow + (((unsigned)(16*g)) ^ pkey));
      pa1u.u4 = *(const uint4*)(prow + (((unsigned)(64 + 16*g)) ^ pkey));
      s8v pa0 = pa0u.s, pa1 = pa1u.s;
      #pragma unroll
      for (int u = 0; u < 8; ++u) {
        const unsigned short* vrow = VTs + (16*u + l15)*72;
        union { uint4 u4; s8v s; } b0, b1;
        b0.u4 = *(const uint4*)(vrow + 8*g);
        b1.u4 = *(const uint4*)(vrow + 32 + 8*g);
        oacc[u] = __builtin_amdgcn_mfma_f32_16x16x32_bf16(pa0, b0.s, oacc[u], 0, 0, 0);
        oacc[u] = __builtin_amdgcn_mfma_f32_16x16x32_bf16(pa1, b1.s, oacc[u], 0, 0, 0);
      }
    }
  }

  // ---- epilogue: cache = o - spo/l ----
  {
    float inv[4];
    #pragma unroll
    for (int r = 0; r < 4; ++r) inv[r] = 1.0f / ll[r];
    #pragma unroll
    for (int t = 0; t < 8; ++t) {
      #pragma unroll
      for (int r = 0; r < 4; ++r) {
        int row = q0 + 16*wv + 4*g + r;
        size_t off = hqk + (size_t)row*Dh + 16*t + l15;
        Out[OUT_HALF + off] = Out[off] - oacc[t][r] * inv[r];
      }
    }
  }
}

// --------- selection: radix top-k + exact fp32 window + random mask ---------
__global__ __launch_bounds__(256) void select_kernel(
    const float* __restrict__ csPart, const int* __restrict__ topkPtr,
    const float* __restrict__ Qm, const float* __restrict__ Km,
    const float* __restrict__ PL,
    int* __restrict__ idxList, int* __restrict__ nSel)
{
  __shared__ uint32_t ubits[N];
  __shared__ int hist[256];
  __shared__ int cnt1[256], base1[256];
  __shared__ int sh_digit, sh_kk, sh_total, sh_A, sh_C;
  __shared__ float kcol[128];
  __shared__ float exacc[4];
  __shared__ int candIdx[CAND_MAX];
  __shared__ float candEx[CAND_MAX];
  __shared__ unsigned char candSel[CAND_MAX];
  __shared__ unsigned char selmap[N];

  const int bh = blockIdx.x;
  const int h = bh >> 4, g = bh & 15;
  const int tid = threadIdx.x;

  // 2-slice fixed-order sum of per-block colsum partials for group g
  const int bA = (3*g) >> 1;
  const int sA = g & 1;
  const int bB = bA + 1;
  const float* pA = csPart + (((size_t)(h*NBD + bA))*2 + sA)*N;
  const float* pB = csPart + (((size_t)(h*NBD + bB))*2 + 0)*N;
  for (int c = tid; c < N; c += 256) {
    float v = pA[c] + pB[c];
    ubits[c] = __float_as_uint(v);
    selmap[c] = 0;
  }
  __syncthreads();

  const int K = topkPtr[0];
  uint32_t prefix = 0; int kk = K;
  for (int pass = 0; pass < 4; ++pass) {
    const int shift = 24 - 8*pass;
    const uint32_t hm = (pass == 0) ? 0u : (0xFFFFFFFFu << (shift + 8));
    hist[tid] = 0;
    __syncthreads();
    for (int c = tid; c < N; c += 256) {
      uint32_t b = ubits[c];
      if ((b & hm) == (prefix & hm)) atomicAdd(&hist[(b >> shift) & 255], 1);
    }
    __syncthreads();
    if (tid == 0) {
      int cum = 0, d = 255;
      for (; d > 0; --d) { int hc = hist[d]; if (cum + hc >= kk) break; cum += hc; }
      sh_digit = d; sh_kk = kk - cum;
    }
    __syncthreads();
    prefix |= ((uint32_t)sh_digit) << shift;
    kk = sh_kk;
    __syncthreads();
  }
  const float thrv = __uint_as_float(prefix);
  const float hiv  = thrv * 1.001f;
  const float lov  = thrv * 0.999f;

  if (tid == 0) { sh_A = 0; sh_C = 0; }
  __syncthreads();
  const int CH = N / 256;
  const int c0 = tid * CH;
  int myIn = 0;
  for (int j = 0; j < CH; ++j) {
    float v = __uint_as_float(ubits[c0 + j]);
    if (v > hiv) myIn++;
    else if (v >= lov) {
      int slot = atomicAdd(&sh_C, 1);
      if (slot < CAND_MAX) candIdx[slot] = c0 + j;
    }
  }
  atomicAdd(&sh_A, myIn);
  __syncthreads();
  const int A = sh_A;
  const int C = min(sh_C, CAND_MAX);
  int need = K - A;
  if (need < 0) need = 0;
  if (need > C) need = C;

  const float* Qg = Qm + (size_t)h*HEAD_STRIDE + (size_t)(g*192)*Dh;
  const float* Kg = Km + (size_t)h*HEAD_STRIDE;
  const float  plq = (tid < 192) ? PL[(size_t)h*N + g*192 + tid] : 0.f;
  for (int ci = 0; ci < C; ++ci) {
    int c = candIdx[ci];
    if (tid < 128) kcol[tid] = Kg[(size_t)c*Dh + tid];
    __syncthreads();
    float e = 0.f;
    if (tid < 192) {
      const float* qr = Qg + (size_t)tid*Dh;
      float acc = 0.f;
      #pragma unroll
      for (int d4 = 0; d4 < 32; ++d4) {
        float4 qv = *(const float4*)(qr + d4*4);
        acc += qv.x*kcol[d4*4] + qv.y*kcol[d4*4+1] + qv.z*kcol[d4*4+2] + qv.w*kcol[d4*4+3];
      }
      e = expf(acc*SCALE - plq);
    }
    #pragma unroll
    for (int s = 1; s < 64; s <<= 1) e += __shfl_xor(e, s);
    if ((tid & 63) == 0) exacc[tid >> 6] = e;
    __syncthreads();
    if (tid == 0) candEx[ci] = (exacc[0] + exacc[1]) + (exacc[2] + exacc[3]);
    __syncthreads();
  }

  if (tid < C) {
    float ei = candEx[tid]; int ii = candIdx[tid];
    int rank = 0;
    for (int j = 0; j < C; ++j) {
      float ej = candEx[j];
      if (ej > ei || (ej == ei && candIdx[j] < ii)) ++rank;
    }
    candSel[tid] = (rank < need) ? 1 : 0;
  }
  __syncthreads();
  if (tid < C && candSel[tid]) selmap[candIdx[tid]] = 1;
  __syncthreads();

  bool fl[12]; int selc = 0;
  for (int j = 0; j < CH; ++j) {
    int c = c0 + j;
    float v = __uint_as_float(ubits[c]);
    bool s = (v > hiv) || (selmap[c] != 0);
    if (!s) s = jax_rand_zero((uint32_t)bh * (uint32_t)N + (uint32_t)c);
    fl[j] = s; selc += s ? 1 : 0;
  }
  cnt1[tid] = selc;
  __syncthreads();
  if (tid == 0) { int run = 0; for (int t = 0; t < 256; ++t) { base1[t] = run; run += cnt1[t]; } sh_total = run; }
  __syncthreads();
  int w = base1[tid];
  int* il = idxList + (size_t)bh * IDXCAP;
  for (int j = 0; j < CH; ++j) if (fl[j]) { if (w < IDXCAP) il[w] = c0 + j; ++w; }
  if (tid == 0) nSel[bh] = (sh_total < IDXCAP) ? sh_total : IDXCAP;
}

// ------------------------------- launch -------------------------------------
extern "C" void kernel_launch(void* const* d_in, const int* in_sizes, int n_in,
                              void* d_out, int out_size, void* d_ws, size_t ws_size,
                              hipStream_t stream) {
  const float* q  = (const float*)d_in[0];
  const float* k  = (const float*)d_in[1];
  const float* v  = (const float*)d_in[2];
  const float* pl = (const float*)d_in[3];
  const int* topk = (const int*)d_in[4];
  float* out = (float*)d_out;
  char* ws   = (char*)d_ws;

  float* csPart = (float*)(ws + CS_B);
  int*   idxL   = (int*)(ws + IDX_B);
  int*   nSel   = (int*)(ws + NSEL_B);
  unsigned short* Kh = (unsigned short*)(ws + KH_B);
  unsigned short* Kl = (unsigned short*)(ws + KL_B);
  unsigned short* Vt = (unsigned short*)(out + OUT_HALF);  // scratch; only dense reads

  (void)hipFuncSetAttribute((const void*)dense_mfma2_kernel,
      hipFuncAttributeMaxDynamicSharedMemorySize, DENSE_SM);
  (void)hipFuncSetAttribute((const void*)sparse_mfma_kernel,
      hipFuncAttributeMaxDynamicSharedMemorySize, SPMF_SM);

  split_bf16_kernel<<<6144, 256, 0, stream>>>(k, Kh, Kl);
  transpose_v_kernel<<<dim3(H, N/64), 256, 0, stream>>>(v, Vt);
  dense_mfma2_kernel<<<384, 256, DENSE_SM, stream>>>(q, Kh, Kl, Vt, pl, out, csPart);
  select_kernel<<<dim3(H * M), 256, 0, stream>>>(csPart, topk, q, k, pl, idxL, nSel);
  sparse_mfma_kernel<<<768, 256, SPMF_SM, stream>>>(q, Kh, Kl, v, idxL, nSel, out);
}

// Round 7
// 723.474 us; speedup vs baseline: 1.3943x; 1.3943x over previous
//
#include <hip/hip_runtime.h>
#include <stdint.h>

// ---------------------------------------------------------------------------
// SparseDiffAttention R6: dense flash attn on 32x32x16 MFMA with SWAPPED
// operands (S^T = K·Q^T, per-lane-scalar softmax state, cvt_pk+permlane32_swap
// P redistribution, LDS-transposed epilogue). 192q blocks = 1 group = 1 block
// = 1 CU. Sparse/select/pre unchanged (proven R5).
// ---------------------------------------------------------------------------

#define JAX_PARTITIONABLE 1

namespace {
constexpr int H   = 16;
constexpr int N   = 3072;
constexpr int Dh  = 128;
constexpr int M   = 16;
constexpr int TK  = 64;
constexpr int NT  = N / TK;        // 48
constexpr float SCALE = 0.08838834764831845f;
constexpr size_t HEAD_STRIDE = (size_t)N * Dh;
constexpr size_t OUT_HALF    = (size_t)H * N * Dh;

constexpr int IDXCAP = 1024;
constexpr int CAND_MAX = 128;

// dense kernel: 6 waves x 32q = 192q = one colsum group per block
constexpr int D_KH  = 0;           // [64c][128d] bf16 swz, 16384
constexpr int D_KL  = 16384;
constexpr int D_VT  = 32768;       // [128d][64c] bf16 swz, 16384
constexpr int D_CSR = 49152;       // 6 x 64 f32
constexpr int DENSE_SM = 50688;    // epilogue reuses bytes [0,49152) as OT

// sparse kernel geometry (proven R4/R5 structure)
constexpr int BQ  = 64;
constexpr int NQB = N / BQ;        // 48
constexpr int SP_KH  = 0;
constexpr int SP_KL  = 16384;
constexpr int SP_VT  = 32768;      // [128 d][72 shorts] (144B rows)
constexpr int SP_PB  = 51200;
constexpr int SP_IDX = 59392;
constexpr int SPMF_SM = 59648;

// ws layout (bytes)
constexpr size_t CS_B   = 0;                        // [H][16][N] f32 = 3.1MB
constexpr size_t IDX_B  = 9437184;
constexpr size_t NSEL_B = IDX_B + (size_t)H*M*IDXCAP*4;
constexpr size_t KH_B   = NSEL_B + 1024;
constexpr size_t KL_B   = KH_B + 12582912;
}

typedef float f4v  __attribute__((ext_vector_type(4)));
typedef float f16v __attribute__((ext_vector_type(16)));
typedef short s8v  __attribute__((ext_vector_type(8)));

__device__ __forceinline__ unsigned short f2bf(float x) {
  unsigned u = __float_as_uint(x);
  unsigned r = u + 0x7FFFu + ((u >> 16) & 1u);
  return (unsigned short)(r >> 16);
}
__device__ __forceinline__ float bf2f(unsigned short b) {
  return __uint_as_float(((unsigned)b) << 16);
}

// P-fragment builders: cvt_pk pairs + permlane32_swap half exchange
#if __has_builtin(__builtin_amdgcn_permlane32_swap)
#define PLSWAP(a, b) do { \
  auto _r = __builtin_amdgcn_permlane32_swap(a, b, false, false); \
  a = _r[0]; b = _r[1]; \
} while (0)
#else
#define PLSWAP(a, b) \
  asm volatile("v_permlane32_swap_b32 %0, %1" : "+v"(a), "+v"(b))
#endif

#define MAKE_PFRAG(dst, a0,a1,a2,a3,a4,a5,a6,a7) do { \
  unsigned w01_, w23_, w45_, w67_; \
  asm("v_cvt_pk_bf16_f32 %0, %1, %2" : "=v"(w01_) : "v"(a0), "v"(a1)); \
  asm("v_cvt_pk_bf16_f32 %0, %1, %2" : "=v"(w23_) : "v"(a2), "v"(a3)); \
  asm("v_cvt_pk_bf16_f32 %0, %1, %2" : "=v"(w45_) : "v"(a4), "v"(a5)); \
  asm("v_cvt_pk_bf16_f32 %0, %1, %2" : "=v"(w67_) : "v"(a6), "v"(a7)); \
  PLSWAP(w01_, w45_); \
  PLSWAP(w23_, w67_); \
  union { unsigned u[4]; s8v s; } r_; \
  r_.u[0] = w01_; r_.u[1] = w23_; r_.u[2] = w45_; r_.u[3] = w67_; \
  dst = r_.s; \
} while (0)

// ------------------------------ threefry -----------------------------------
__device__ __forceinline__ void tf_round(uint32_t& x0, uint32_t& x1, int r) {
  x0 += x1; x1 = (x1 << r) | (x1 >> (32 - r)); x1 ^= x0;
}
__device__ __forceinline__ void tf2x32(uint32_t k0, uint32_t k1,
                                       uint32_t x0, uint32_t x1,
                                       uint32_t& y0, uint32_t& y1) {
  uint32_t k2 = k0 ^ k1 ^ 0x1BD11BDAu;
  x0 += k0; x1 += k1;
  tf_round(x0,x1,13); tf_round(x0,x1,15); tf_round(x0,x1,26); tf_round(x0,x1,6);
  x0 += k1; x1 += k2 + 1u;
  tf_round(x0,x1,17); tf_round(x0,x1,29); tf_round(x0,x1,16); tf_round(x0,x1,24);
  x0 += k2; x1 += k0 + 2u;
  tf_round(x0,x1,13); tf_round(x0,x1,15); tf_round(x0,x1,26); tf_round(x0,x1,6);
  x0 += k0; x1 += k1 + 3u;
  tf_round(x0,x1,17); tf_round(x0,x1,29); tf_round(x0,x1,16); tf_round(x0,x1,24);
  x0 += k1; x1 += k2 + 4u;
  tf_round(x0,x1,13); tf_round(x0,x1,15); tf_round(x0,x1,26); tf_round(x0,x1,6);
  x0 += k2; x1 += k0 + 5u;
  y0 = x0; y1 = x1;
}

__device__ __forceinline__ bool jax_rand_zero(uint32_t idx) {
  uint32_t hi, lo, r0, r1;
#if JAX_PARTITIONABLE
  uint32_t a0,a1,b0,b1;
  tf2x32(0u,42u, 0u,0u, a0,a1);
  tf2x32(0u,42u, 0u,1u, b0,b1);
  tf2x32(a0,a1, 0u, idx, r0,r1);  hi = r0 ^ r1;
  tf2x32(b0,b1, 0u, idx, r0,r1);  lo = r0 ^ r1;
#else
  uint32_t p0x,p0y,p1x,p1y;
  tf2x32(0u,42u, 0u,2u, p0x,p0y);
  tf2x32(0u,42u, 1u,3u, p1x,p1y);
  const uint32_t half = (uint32_t)((size_t)H*M*N) / 2u;
  uint32_t i = (idx < half) ? idx : (idx - half);
  uint32_t h0,h1,l0,l1;
  tf2x32(p0x, p1x, i, i + half, h0, h1);
  tf2x32(p0y, p1y, i, i + half, l0, l1);
  hi = (idx < half) ? h0 : h1;
  lo = (idx < half) ? l0 : l1;
#endif
  uint32_t off = ((hi % 100u) * 96u + (lo % 100u)) % 100u;
  return off == 0u;
}

// ----------------------- precompute: K -> Kh,Kl bf16 ------------------------
__global__ __launch_bounds__(256) void split_bf16_kernel(
    const float* __restrict__ K, unsigned short* __restrict__ Kh,
    unsigned short* __restrict__ Kl)
{
  size_t i = ((size_t)blockIdx.x * 256 + threadIdx.x) * 4;
  float4 v = *(const float4*)(K + i);
  unsigned short h0 = f2bf(v.x), h1 = f2bf(v.y), h2 = f2bf(v.z), h3 = f2bf(v.w);
  unsigned short l0 = f2bf(v.x - bf2f(h0)), l1 = f2bf(v.y - bf2f(h1));
  unsigned short l2 = f2bf(v.z - bf2f(h2)), l3 = f2bf(v.w - bf2f(h3));
  uint2 hu, lu;
  hu.x = (unsigned)h0 | ((unsigned)h1 << 16); hu.y = (unsigned)h2 | ((unsigned)h3 << 16);
  lu.x = (unsigned)l0 | ((unsigned)l1 << 16); lu.y = (unsigned)l2 | ((unsigned)l3 << 16);
  *(uint2*)(Kh + i) = hu;
  *(uint2*)(Kl + i) = lu;
}

// ----------------------- precompute: V -> Vt bf16 [H][Dh][N] ----------------
__global__ __launch_bounds__(256) void transpose_v_kernel(
    const float* __restrict__ Vm, unsigned short* __restrict__ Vt)
{
  __shared__ unsigned short tb[64][132];
  const int h  = blockIdx.x;
  const int cb = blockIdx.y;
  const int tid = threadIdx.x;
  const float* vg = Vm + (size_t)h*HEAD_STRIDE + (size_t)(cb*64)*Dh;
  #pragma unroll
  for (int it = 0; it < 8; ++it) {
    int f = tid + 256*it;
    int c = f >> 5, d0 = (f & 31)*4;
    float4 v = *(const float4*)(vg + c*Dh + d0);
    tb[c][d0+0] = f2bf(v.x); tb[c][d0+1] = f2bf(v.y);
    tb[c][d0+2] = f2bf(v.z); tb[c][d0+3] = f2bf(v.w);
  }
  __syncthreads();
  unsigned short* vt = Vt + (size_t)h*((size_t)Dh*N) + (size_t)(cb*64);
  #pragma unroll
  for (int it = 0; it < 4; ++it) {
    int f = tid + 256*it;
    int d = f >> 3, sl = f & 7;
    union { unsigned short us[8]; uint4 u; } o;
    #pragma unroll
    for (int i = 0; i < 8; ++i) o.us[i] = tb[sl*8 + i][d];
    *(uint4*)(vt + (size_t)d*N + sl*8) = o.u;
  }
}

// ---------- dense flash: 6 waves x 32q, 32x32x16 MFMA, swapped QK^T ---------
__global__ __launch_bounds__(384, 2) void dense_mfma3_kernel(
    const float* __restrict__ Qm, const unsigned short* __restrict__ Khg,
    const unsigned short* __restrict__ Klg, const unsigned short* __restrict__ Vtg,
    const float* __restrict__ PL, float* __restrict__ Out,
    float* __restrict__ csPart)
{
  extern __shared__ char smc[];
  char* KH = smc + D_KH;
  char* KL = smc + D_KL;
  char* VT = smc + D_VT;
  float* CSR = (float*)(smc + D_CSR);

  // 256 blocks, XCD-chunked: 32 per XCD = 2 heads
  const int id  = blockIdx.x;
  const int wid = (id & 7) * 32 + (id >> 3);
  const int h   = wid >> 4;
  const int g   = wid & 15;           // colsum group == block
  const int q0  = g * 192;

  const int tid = threadIdx.x;
  const int wv  = tid >> 6;           // 0..5
  const int ln  = tid & 63;
  const int l31 = ln & 31;
  const int hi  = ln >> 5;
  const size_t hqk = (size_t)h * HEAD_STRIDE;

  // ---- Q fragments: global -> reg, scale, hi/lo split (B-operand layout) ----
  // B[k=d][col=q]: col = lane&31 = q; k-slice d = 16s + 8*hi + j
  s8v qh[8], ql[8];
  {
    const float* qrp = Qm + hqk + (size_t)(q0 + 32*wv + l31) * Dh;
    #pragma unroll
    for (int s = 0; s < 8; ++s) {
      int d0 = 16*s + 8*hi;
      float4 a = *(const float4*)(qrp + d0);
      float4 b = *(const float4*)(qrp + d0 + 4);
      float vals[8] = {a.x,a.y,a.z,a.w,b.x,b.y,b.z,b.w};
      union { unsigned short u[8]; s8v s; } hh, lo;
      #pragma unroll
      for (int j = 0; j < 8; ++j) {
        float x = vals[j] * SCALE;
        unsigned short hb = f2bf(x);
        hh.u[j] = hb;
        lo.u[j] = f2bf(x - bf2f(hb));
      }
      qh[s] = hh.s; ql[s] = lo.s;
    }
  }

  const float plr = PL[(size_t)h*N + q0 + 32*wv + l31];
  float mo = -1e30f, llv = 0.0f;
  f16v oacT[4];
  #pragma unroll
  for (int dt = 0; dt < 4; ++dt)
    #pragma unroll
    for (int r = 0; r < 16; ++r) oacT[dt][r] = 0.0f;

  const unsigned key = ((unsigned)(l31 & 7)) << 4;   // rows c/d: (row&7)==l31&7

  for (int kt = 0; kt < NT; ++kt) {
    // ---- stage KH/KL (2048 u4) + VT (1024 u4); prev reads done at loop-end barrier
    {
      const unsigned short* khg = Khg + hqk + (size_t)(kt*TK) * Dh;
      const unsigned short* klg = Klg + hqk + (size_t)(kt*TK) * Dh;
      #pragma unroll
      for (int i = 0; i < 6; ++i) {
        int f = tid + 384*i;
        if (f < 2048) {
          int pl = f >> 10, e = f & 1023, row = e >> 4, sl = e & 15;
          uint4 v = *(const uint4*)((pl ? klg : khg) + row*Dh + sl*8);
          unsigned off = (unsigned)(row*256) + (((unsigned)(sl*16)) ^ ((unsigned)(row&7) << 4));
          *(uint4*)((pl ? KL : KH) + off) = v;
        }
      }
      const unsigned short* vtg = Vtg + (size_t)h*((size_t)Dh*N) + (size_t)(kt*TK);
      #pragma unroll
      for (int i = 0; i < 3; ++i) {
        int f = tid + 384*i;
        if (f < 1024) {
          int d = f >> 3, sl = f & 7;
          uint4 v = *(const uint4*)(vtg + (size_t)d*N + sl*8);
          unsigned off = (unsigned)(d*128) + (((unsigned)(sl*16)) ^ ((unsigned)(d&7) << 4));
          *(uint4*)(VT + off) = v;
        }
      }
    }
    __syncthreads();

    // ---- QK^T (swapped): S^T[c][q], A = K rows c = 32ct+l31, B = Q^T ----
    f16v S0, S1;
    #pragma unroll
    for (int r = 0; r < 16; ++r) { S0[r] = 0.0f; S1[r] = 0.0f; }
    #pragma unroll
    for (int s = 0; s < 8; ++s) {
      unsigned doff = (unsigned)(s*32 + 16*hi);
      unsigned o0 = (unsigned)(l31*256) + (doff ^ key);
      unsigned o1 = o0 + 32*256;
      union { uint4 u; s8v v; } kh0, kl0, kh1, kl1;
      kh0.u = *(const uint4*)(KH + o0);
      kl0.u = *(const uint4*)(KL + o0);
      kh1.u = *(const uint4*)(KH + o1);
      kl1.u = *(const uint4*)(KL + o1);
      S0 = __builtin_amdgcn_mfma_f32_32x32x16_bf16(kh0.v, qh[s], S0, 0, 0, 0);
      S1 = __builtin_amdgcn_mfma_f32_32x32x16_bf16(kh1.v, qh[s], S1, 0, 0, 0);
      S0 = __builtin_amdgcn_mfma_f32_32x32x16_bf16(kh0.v, ql[s], S0, 0, 0, 0);
      S1 = __builtin_amdgcn_mfma_f32_32x32x16_bf16(kh1.v, ql[s], S1, 0, 0, 0);
      S0 = __builtin_amdgcn_mfma_f32_32x32x16_bf16(kl0.v, qh[s], S0, 0, 0, 0);
      S1 = __builtin_amdgcn_mfma_f32_32x32x16_bf16(kl1.v, qh[s], S1, 0, 0, 0);
    }

    // ---- online softmax: state is per-lane scalar (q = l31) ----
    float vmax = S0[0];
    #pragma unroll
    for (int r = 1; r < 16; ++r) vmax = fmaxf(vmax, S0[r]);
    #pragma unroll
    for (int r = 0; r < 16; ++r) vmax = fmaxf(vmax, S1[r]);
    vmax = fmaxf(vmax, __shfl_xor(vmax, 32));
    const float mn = fmaxf(mo, vmax);
    const float sc = __expf(mo - mn);
    const float wq = __expf(mn - plr);
    mo = mn;

    float p0[16], p1[16];
    float rs = 0.0f;
    #pragma unroll
    for (int r = 0; r < 16; ++r) { p0[r] = __expf(S0[r] - mn); rs += p0[r]; }
    #pragma unroll
    for (int r = 0; r < 16; ++r) { p1[r] = __expf(S1[r] - mn); rs += p1[r]; }
    rs += __shfl_xor(rs, 32);
    llv = llv * sc + rs;

    // ---- colsum: cs[c] = sum_q p*wq ; c = 32T + (i&3)+8*(i>>2)+4*hi ----
    #pragma unroll
    for (int i = 0; i < 16; ++i) {
      float cv = p0[i] * wq;
      cv += __shfl_xor(cv, 1);  cv += __shfl_xor(cv, 2);
      cv += __shfl_xor(cv, 4);  cv += __shfl_xor(cv, 8);
      cv += __shfl_xor(cv, 16);
      if ((ln & 31) == 0) CSR[wv*64 + (i&3) + 8*(i>>2) + 4*hi] = cv;
    }
    #pragma unroll
    for (int i = 0; i < 16; ++i) {
      float cv = p1[i] * wq;
      cv += __shfl_xor(cv, 1);  cv += __shfl_xor(cv, 2);
      cv += __shfl_xor(cv, 4);  cv += __shfl_xor(cv, 8);
      cv += __shfl_xor(cv, 16);
      if ((ln & 31) == 0) CSR[wv*64 + 32 + (i&3) + 8*(i>>2) + 4*hi] = cv;
    }

    // ---- rescale O^T accumulator (per-lane scalar) ----
    #pragma unroll
    for (int dt = 0; dt < 4; ++dt)
      #pragma unroll
      for (int r = 0; r < 16; ++r) oacT[dt][r] *= sc;

    // ---- P fragments via cvt_pk + permlane32_swap (no LDS) ----
    s8v pf0, pf1, pf2, pf3;
    MAKE_PFRAG(pf0, p0[0],p0[1],p0[2],p0[3],p0[4],p0[5],p0[6],p0[7]);
    MAKE_PFRAG(pf1, p0[8],p0[9],p0[10],p0[11],p0[12],p0[13],p0[14],p0[15]);
    MAKE_PFRAG(pf2, p1[0],p1[1],p1[2],p1[3],p1[4],p1[5],p1[6],p1[7]);
    MAKE_PFRAG(pf3, p1[8],p1[9],p1[10],p1[11],p1[12],p1[13],p1[14],p1[15]);

    // ---- PV: O^T[d][q] += V^T-frag x P-frag ----
    #pragma unroll
    for (int dt = 0; dt < 4; ++dt) {
      unsigned dbase = (unsigned)((32*dt + l31) * 128);
      union { uint4 u; s8v v; } v0, v1, v2, v3;
      v0.u = *(const uint4*)(VT + dbase + (((unsigned)(0*32 + 16*hi)) ^ key));
      v1.u = *(const uint4*)(VT + dbase + (((unsigned)(1*32 + 16*hi)) ^ key));
      v2.u = *(const uint4*)(VT + dbase + (((unsigned)(2*32 + 16*hi)) ^ key));
      v3.u = *(const uint4*)(VT + dbase + (((unsigned)(3*32 + 16*hi)) ^ key));
      oacT[dt] = __builtin_amdgcn_mfma_f32_32x32x16_bf16(v0.v, pf0, oacT[dt], 0, 0, 0);
      oacT[dt] = __builtin_amdgcn_mfma_f32_32x32x16_bf16(v1.v, pf1, oacT[dt], 0, 0, 0);
      oacT[dt] = __builtin_amdgcn_mfma_f32_32x32x16_bf16(v2.v, pf2, oacT[dt], 0, 0, 0);
      oacT[dt] = __builtin_amdgcn_mfma_f32_32x32x16_bf16(v3.v, pf3, oacT[dt], 0, 0, 0);
    }
    __syncthreads();

    // ---- block colsum -> global (group g owned exclusively) ----
    if (tid < 64) {
      float c = ((CSR[tid] + CSR[64 + tid]) + (CSR[128 + tid] + CSR[192 + tid]))
              + (CSR[256 + tid] + CSR[320 + tid]);
      csPart[((size_t)(h*M + g))*N + kt*TK + tid] = c;
    }
  }

  // ---- epilogue: O^T regs -> LDS transpose -> coalesced global (2 passes) ----
  {
    const float inv = 1.0f / llv;
    #pragma unroll
    for (int dt = 0; dt < 4; ++dt)
      #pragma unroll
      for (int r = 0; r < 16; ++r) oacT[dt][r] *= inv;

    #pragma unroll
    for (int pass = 0; pass < 2; ++pass) {
      __syncthreads();
      if (wv >= 3*pass && wv < 3*pass + 3) {
        int qr = 32*(wv - 3*pass) + l31;              // 0..95
        unsigned qkey = ((unsigned)(qr & 7)) << 4;
        #pragma unroll
        for (int dt = 0; dt < 4; ++dt)
          #pragma unroll
          for (int G = 0; G < 4; ++G) {
            unsigned off = (unsigned)(qr*512) +
                (((unsigned)(dt*128 + G*32 + hi*16)) ^ qkey);
            float4 w;
            w.x = oacT[dt][4*G];   w.y = oacT[dt][4*G+1];
            w.z = oacT[dt][4*G+2]; w.w = oacT[dt][4*G+3];
            *(float4*)(smc + off) = w;
          }
      }
      __syncthreads();
      #pragma unroll
      for (int it = 0; it < 8; ++it) {
        int f = tid + 384*it;
        if (f < 3072) {
          int row = f >> 5, ds = f & 31;
          float4 v = *(const float4*)(smc + row*512 +
              (((unsigned)(ds*16)) ^ (((unsigned)(row & 7)) << 4)));
          *(float4*)(Out + hqk + (size_t)(q0 + 96*pass + row)*Dh + ds*4) = v;
        }
      }
    }
  }
}

// --------------------- sparse MFMA flash + out_cache (R5) -------------------
__global__ __launch_bounds__(256, 2) void sparse_mfma_kernel(
    const float* __restrict__ Qm, const unsigned short* __restrict__ Khg,
    const unsigned short* __restrict__ Klg, const float* __restrict__ Vm,
    const int* __restrict__ idxList, const int* __restrict__ nSel,
    float* __restrict__ Out)
{
  extern __shared__ char smc[];
  char* KH = smc + SP_KH;
  char* KL = smc + SP_KL;
  unsigned short* VTs = (unsigned short*)(smc + SP_VT);   // [128][72]
  char* PB = smc + SP_PB;
  int* idxs = (int*)(smc + SP_IDX);

  const int id  = blockIdx.x;
  const int wid = (id & 7) * 96 + (id >> 3);
  const int h   = wid / NQB;
  const int qb  = wid % NQB;
  const int gq  = qb / 3;
  const int q0  = qb * BQ;

  const int tid = threadIdx.x;
  const int wv  = tid >> 6;
  const int ln  = tid & 63;
  const int g   = ln >> 4;
  const int l15 = ln & 15;

  const size_t hqk = (size_t)h * HEAD_STRIDE;

  {
    const float* qg = Qm + hqk + (size_t)q0 * Dh;
    #pragma unroll
    for (int it = 0; it < 8; ++it) {
      int f = tid + 256*it;
      int row = f >> 5, d0 = (f & 31) * 4;
      float4 v = *(const float4*)(qg + row*Dh + d0);
      v.x *= SCALE; v.y *= SCALE; v.z *= SCALE; v.w *= SCALE;
      unsigned short h0 = f2bf(v.x), h1 = f2bf(v.y), h2 = f2bf(v.z), h3 = f2bf(v.w);
      unsigned short o0 = f2bf(v.x - bf2f(h0)), o1 = f2bf(v.y - bf2f(h1));
      unsigned short o2 = f2bf(v.z - bf2f(h2)), o3 = f2bf(v.w - bf2f(h3));
      unsigned off = (unsigned)(row*256) + (((unsigned)(d0*2)) ^ ((unsigned)(row&7) << 4));
      uint2 hu, lu;
      hu.x = (unsigned)h0 | ((unsigned)h1<<16); hu.y = (unsigned)h2 | ((unsigned)h3<<16);
      lu.x = (unsigned)o0 | ((unsigned)o1<<16); lu.y = (unsigned)o2 | ((unsigned)o3<<16);
      *(uint2*)(KH + off) = hu;
      *(uint2*)(KL + off) = lu;
    }
  }
  __syncthreads();
  s8v qh[4], qlo[4];
  {
    const int qrow = 16*wv + l15;
    const unsigned qswz = ((unsigned)(qrow & 7)) << 4;
    #pragma unroll
    for (int k0i = 0; k0i < 4; ++k0i) {
      unsigned off = (unsigned)(qrow*256) + (((unsigned)((k0i*4 + g)*16)) ^ qswz);
      union { uint4 u; s8v s; } a, b;
      a.u = *(const uint4*)(KH + off);
      b.u = *(const uint4*)(KL + off);
      qh[k0i] = a.s; qlo[k0i] = b.s;
    }
  }

  float mo[4], ll[4];
  #pragma unroll
  for (int r = 0; r < 4; ++r) { mo[r] = -1e30f; ll[r] = 0.0f; }
  f4v oacc[8];
  #pragma unroll
  for (int t = 0; t < 8; ++t) oacc[t] = (f4v){0.f, 0.f, 0.f, 0.f};

  const unsigned kswz = ((unsigned)(l15 & 7)) << 4;

  int nsel = nSel[h*M + gq];
  if (nsel > IDXCAP) nsel = IDXCAP;
  const int* il = idxList + ((size_t)h*M + gq) * IDXCAP;
  const int nt = (nsel + TK - 1) / TK;

  for (int t = 0; t < nt; ++t) {
    const int cnt = min(TK, nsel - t*TK);
    __syncthreads();
    if (tid < 64) idxs[tid] = (tid < cnt) ? il[t*TK + tid] : 0;
    __syncthreads();

    {
      const int row = tid & 63;
      const int c = idxs[row];
      const unsigned short* khr = Khg + hqk + (size_t)c * Dh;
      const unsigned short* klr = Klg + hqk + (size_t)c * Dh;
      const unsigned swz = ((unsigned)(row & 7)) << 4;
      #pragma unroll
      for (int j = 0; j < 4; ++j) {
        int chunk = (tid >> 6) + 4*j;
        unsigned off = (unsigned)(row*256) + (((unsigned)(chunk*16)) ^ swz);
        *(uint4*)(KH + off) = *(const uint4*)(khr + chunk*8);
        *(uint4*)(KL + off) = *(const uint4*)(klr + chunk*8);
      }
      const int q4 = tid & 15;
      const int seg = tid >> 4;
      int c4[4];
      #pragma unroll
      for (int j = 0; j < 4; ++j) c4[j] = idxs[4*q4 + j];
      union { float4 f4[2]; float f[8]; } col[4];
      #pragma unroll
      for (int j = 0; j < 4; ++j) {
        const float* vr = Vm + hqk + (size_t)c4[j]*Dh + 8*seg;
        col[j].f4[0] = *(const float4*)(vr);
        col[j].f4[1] = *(const float4*)(vr + 4);
      }
      #pragma unroll
      for (int dd = 0; dd < 8; ++dd) {
        unsigned short b0 = f2bf(col[0].f[dd]), b1 = f2bf(col[1].f[dd]);
        unsigned short b2 = f2bf(col[2].f[dd]), b3 = f2bf(col[3].f[dd]);
        uint2 pk;
        pk.x = (unsigned)b0 | ((unsigned)b1 << 16);
        pk.y = (unsigned)b2 | ((unsigned)b3 << 16);
        *(uint2*)((char*)VTs + (8*seg + dd)*144 + q4*8) = pk;
      }
    }
    __syncthreads();

    f4v S[4];
    #pragma unroll
    for (int u = 0; u < 4; ++u) S[u] = (f4v){0.f, 0.f, 0.f, 0.f};
    #pragma unroll
    for (int k0i = 0; k0i < 4; ++k0i) {
      #pragma unroll
      for (int u = 0; u < 4; ++u) {
        unsigned off = (unsigned)(u*4096 + l15*256) + (((unsigned)((k0i*4 + g)*16)) ^ kswz);
        union { uint4 u4; s8v s; } kh_, kl_;
        kh_.u4 = *(const uint4*)(KH + off);
        kl_.u4 = *(const uint4*)(KL + off);
        S[u] = __builtin_amdgcn_mfma_f32_16x16x32_bf16(qh[k0i], kh_.s, S[u], 0, 0, 0);
        S[u] = __builtin_amdgcn_mfma_f32_16x16x32_bf16(qh[k0i], kl_.s, S[u], 0, 0, 0);
        S[u] = __builtin_amdgcn_mfma_f32_16x16x32_bf16(qlo[k0i], kh_.s, S[u], 0, 0, 0);
      }
    }
    #pragma unroll
    for (int u = 0; u < 4; ++u)
      if (16*u + l15 >= cnt) S[u] = (f4v){-1e30f, -1e30f, -1e30f, -1e30f};

    float sc[4], p[4][4];
    #pragma unroll
    for (int r = 0; r < 4; ++r) {
      float v = fmaxf(fmaxf(S[0][r], S[1][r]), fmaxf(S[2][r], S[3][r]));
      v = fmaxf(v, __shfl_xor(v, 1)); v = fmaxf(v, __shfl_xor(v, 2));
      v = fmaxf(v, __shfl_xor(v, 4)); v = fmaxf(v, __shfl_xor(v, 8));
      float mn = fmaxf(mo[r], v);
      sc[r] = __expf(mo[r] - mn);
      mo[r] = mn;
    }
    #pragma unroll
    for (int r = 0; r < 4; ++r) {
      float rs = 0.f;
      #pragma unroll
      for (int u = 0; u < 4; ++u) { float pv = __expf(S[u][r] - mo[r]); p[u][r] = pv; rs += pv; }
      rs += __shfl_xor(rs, 1); rs += __shfl_xor(rs, 2);
      rs += __shfl_xor(rs, 4); rs += __shfl_xor(rs, 8);
      ll[r] = ll[r]*sc[r] + rs;
    }
    #pragma unroll
    for (int u = 0; u < 8; ++u) {
      f4v o = oacc[u];
      o[0] *= sc[0]; o[1] *= sc[1]; o[2] *= sc[2]; o[3] *= sc[3];
      oacc[u] = o;
    }
    #pragma unroll
    for (int r = 0; r < 4; ++r) {
      int qlr = 4*g + r;
      unsigned pkey = ((unsigned)((qlr >> 1) & 7)) << 4;
      char* rowp = PB + wv*2048 + qlr*128;
      #pragma unroll
      for (int u = 0; u < 4; ++u) {
        unsigned off = ((unsigned)(32*u + 2*l15)) ^ pkey;
        *(unsigned short*)(rowp + off) = f2bf(p[u][r]);
      }
    }
    __syncthreads();

    {
      const unsigned pkey = ((unsigned)((l15 >> 1) & 7)) << 4;
      const char* prow = PB + wv*2048 + l15*128;
      union { uint4 u4; s8v s; } pa0u, pa1u;
      pa0u.u4 = *(const uint4*)(prow + (((unsigned)(16*g)) ^ pkey));
      pa1u.u4 = *(const uint4*)(prow + (((unsigned)(64 + 16*g)) ^ pkey));
      s8v pa0 = pa0u.s, pa1 = pa1u.s;
      #pragma unroll
      for (int u = 0; u < 8; ++u) {
        const unsigned short* vrow = VTs + (16*u + l15)*72;
        union { uint4 u4; s8v s; } b0, b1;
        b0.u4 = *(const uint4*)(vrow + 8*g);
        b1.u4 = *(const uint4*)(vrow + 32 + 8*g);
        oacc[u] = __builtin_amdgcn_mfma_f32_16x16x32_bf16(pa0, b0.s, oacc[u], 0, 0, 0);
        oacc[u] = __builtin_amdgcn_mfma_f32_16x16x32_bf16(pa1, b1.s, oacc[u], 0, 0, 0);
      }
    }
  }

  {
    float inv[4];
    #pragma unroll
    for (int r = 0; r < 4; ++r) inv[r] = 1.0f / ll[r];
    #pragma unroll
    for (int t = 0; t < 8; ++t) {
      #pragma unroll
      for (int r = 0; r < 4; ++r) {
        int row = q0 + 16*wv + 4*g + r;
        size_t off = hqk + (size_t)row*Dh + 16*t + l15;
        Out[OUT_HALF + off] = Out[off] - oacc[t][r] * inv[r];
      }
    }
  }
}

// --------- selection: radix top-k + exact fp32 window + random mask ---------
__global__ __launch_bounds__(256) void select_kernel(
    const float* __restrict__ csPart, const int* __restrict__ topkPtr,
    const float* __restrict__ Qm, const float* __restrict__ Km,
    const float* __restrict__ PL,
    int* __restrict__ idxList, int* __restrict__ nSel)
{
  __shared__ uint32_t ubits[N];
  __shared__ int hist[256];
  __shared__ int cnt1[256], base1[256];
  __shared__ int sh_digit, sh_kk, sh_total, sh_A, sh_C;
  __shared__ float kcol[128];
  __shared__ float exacc[4];
  __shared__ int candIdx[CAND_MAX];
  __shared__ float candEx[CAND_MAX];
  __shared__ unsigned char candSel[CAND_MAX];
  __shared__ unsigned char selmap[N];

  const int bh = blockIdx.x;
  const int h = bh >> 4, g = bh & 15;
  const int tid = threadIdx.x;

  const float* p0 = csPart + (size_t)bh * N;
  for (int c = tid; c < N; c += 256) {
    ubits[c] = __float_as_uint(p0[c]);
    selmap[c] = 0;
  }
  __syncthreads();

  const int K = topkPtr[0];
  uint32_t prefix = 0; int kk = K;
  for (int pass = 0; pass < 4; ++pass) {
    const int shift = 24 - 8*pass;
    const uint32_t hm = (pass == 0) ? 0u : (0xFFFFFFFFu << (shift + 8));
    hist[tid] = 0;
    __syncthreads();
    for (int c = tid; c < N; c += 256) {
      uint32_t b = ubits[c];
      if ((b & hm) == (prefix & hm)) atomicAdd(&hist[(b >> shift) & 255], 1);
    }
    __syncthreads();
    if (tid == 0) {
      int cum = 0, d = 255;
      for (; d > 0; --d) { int hc = hist[d]; if (cum + hc >= kk) break; cum += hc; }
      sh_digit = d; sh_kk = kk - cum;
    }
    __syncthreads();
    prefix |= ((uint32_t)sh_digit) << shift;
    kk = sh_kk;
    __syncthreads();
  }
  const float thrv = __uint_as_float(prefix);
  const float hiv  = thrv * 1.001f;
  const float lov  = thrv * 0.999f;

  if (tid == 0) { sh_A = 0; sh_C = 0; }
  __syncthreads();
  const int CH = N / 256;
  const int c0 = tid * CH;
  int myIn = 0;
  for (int j = 0; j < CH; ++j) {
    float v = __uint_as_float(ubits[c0 + j]);
    if (v > hiv) myIn++;
    else if (v >= lov) {
      int slot = atomicAdd(&sh_C, 1);
      if (slot < CAND_MAX) candIdx[slot] = c0 + j;
    }
  }
  atomicAdd(&sh_A, myIn);
  __syncthreads();
  const int A = sh_A;
  const int C = min(sh_C, CAND_MAX);
  int need = K - A;
  if (need < 0) need = 0;
  if (need > C) need = C;

  const float* Qg = Qm + (size_t)h*HEAD_STRIDE + (size_t)(g*192)*Dh;
  const float* Kg = Km + (size_t)h*HEAD_STRIDE;
  const float  plq = (tid < 192) ? PL[(size_t)h*N + g*192 + tid] : 0.f;
  for (int ci = 0; ci < C; ++ci) {
    int c = candIdx[ci];
    if (tid < 128) kcol[tid] = Kg[(size_t)c*Dh + tid];
    __syncthreads();
    float e = 0.f;
    if (tid < 192) {
      const float* qr = Qg + (size_t)tid*Dh;
      float acc = 0.f;
      #pragma unroll
      for (int d4 = 0; d4 < 32; ++d4) {
        float4 qv = *(const float4*)(qr + d4*4);
        acc += qv.x*kcol[d4*4] + qv.y*kcol[d4*4+1] + qv.z*kcol[d4*4+2] + qv.w*kcol[d4*4+3];
      }
      e = expf(acc*SCALE - plq);
    }
    #pragma unroll
    for (int s = 1; s < 64; s <<= 1) e += __shfl_xor(e, s);
    if ((tid & 63) == 0) exacc[tid >> 6] = e;
    __syncthreads();
    if (tid == 0) candEx[ci] = (exacc[0] + exacc[1]) + (exacc[2] + exacc[3]);
    __syncthreads();
  }

  if (tid < C) {
    float ei = candEx[tid]; int ii = candIdx[tid];
    int rank = 0;
    for (int j = 0; j < C; ++j) {
      float ej = candEx[j];
      if (ej > ei || (ej == ei && candIdx[j] < ii)) ++rank;
    }
    candSel[tid] = (rank < need) ? 1 : 0;
  }
  __syncthreads();
  if (tid < C && candSel[tid]) selmap[candIdx[tid]] = 1;
  __syncthreads();

  bool fl[12]; int selc = 0;
  for (int j = 0; j < CH; ++j) {
    int c = c0 + j;
    float v = __uint_as_float(ubits[c]);
    bool s = (v > hiv) || (selmap[c] != 0);
    if (!s) s = jax_rand_zero((uint32_t)bh * (uint32_t)N + (uint32_t)c);
    fl[j] = s; selc += s ? 1 : 0;
  }
  cnt1[tid] = selc;
  __syncthreads();
  if (tid == 0) { int run = 0; for (int t = 0; t < 256; ++t) { base1[t] = run; run += cnt1[t]; } sh_total = run; }
  __syncthreads();
  int w = base1[tid];
  int* il = idxList + (size_t)bh * IDXCAP;
  for (int j = 0; j < CH; ++j) if (fl[j]) { if (w < IDXCAP) il[w] = c0 + j; ++w; }
  if (tid == 0) nSel[bh] = (sh_total < IDXCAP) ? sh_total : IDXCAP;
}

// ------------------------------- launch -------------------------------------
extern "C" void kernel_launch(void* const* d_in, const int* in_sizes, int n_in,
                              void* d_out, int out_size, void* d_ws, size_t ws_size,
                              hipStream_t stream) {
  const float* q  = (const float*)d_in[0];
  const float* k  = (const float*)d_in[1];
  const float* v  = (const float*)d_in[2];
  const float* pl = (const float*)d_in[3];
  const int* topk = (const int*)d_in[4];
  float* out = (float*)d_out;
  char* ws   = (char*)d_ws;

  float* csPart = (float*)(ws + CS_B);
  int*   idxL   = (int*)(ws + IDX_B);
  int*   nSel   = (int*)(ws + NSEL_B);
  unsigned short* Kh = (unsigned short*)(ws + KH_B);
  unsigned short* Kl = (unsigned short*)(ws + KL_B);
  unsigned short* Vt = (unsigned short*)(out + OUT_HALF);  // scratch; only dense reads

  (void)hipFuncSetAttribute((const void*)dense_mfma3_kernel,
      hipFuncAttributeMaxDynamicSharedMemorySize, DENSE_SM);
  (void)hipFuncSetAttribute((const void*)sparse_mfma_kernel,
      hipFuncAttributeMaxDynamicSharedMemorySize, SPMF_SM);

  split_bf16_kernel<<<6144, 256, 0, stream>>>(k, Kh, Kl);
  transpose_v_kernel<<<dim3(H, N/64), 256, 0, stream>>>(v, Vt);
  dense_mfma3_kernel<<<256, 384, DENSE_SM, stream>>>(q, Kh, Kl, Vt, pl, out, csPart);
  select_kernel<<<dim3(H * M), 256, 0, stream>>>(csPart, topk, q, k, pl, idxL, nSel);
  sparse_mfma_kernel<<<768, 256, SPMF_SM, stream>>>(q, Kh, Kl, v, idxL, nSel, out);
}

// Round 8
// 695.523 us; speedup vs baseline: 1.4504x; 1.0402x over previous
//
#include <hip/hip_runtime.h>
#include <stdint.h>

// ---------------------------------------------------------------------------
// SparseDiffAttention R7: dense flash attn on 32x32x16 MFMA, swapped operands,
// double-buffered LDS via global_load_lds (pre-swizzled source, linear dest),
// __launch_bounds__(384,1) to kill VGPR spill. Sparse/select/pre unchanged.
// ---------------------------------------------------------------------------

#define JAX_PARTITIONABLE 1

namespace {
constexpr int H   = 16;
constexpr int N   = 3072;
constexpr int Dh  = 128;
constexpr int M   = 16;
constexpr int TK  = 64;
constexpr int NT  = N / TK;        // 48
constexpr float SCALE = 0.08838834764831845f;
constexpr size_t HEAD_STRIDE = (size_t)N * Dh;
constexpr size_t OUT_HALF    = (size_t)H * N * Dh;

constexpr int IDXCAP = 1024;
constexpr int CAND_MAX = 128;

// dense kernel: 6 waves x 32q = 192q = one colsum group per block
// double-buffered: buf b at smc + b*49152; within buf: KH 16K | KL 16K | VT 16K
constexpr int D_BUF = 49152;
constexpr int D_CSR = 98304;       // 6 x 64 f32
constexpr int DENSE_SM = 99840;    // epilogue reuses [0,98304) as OT

// sparse kernel geometry (proven R4/R5 structure)
constexpr int BQ  = 64;
constexpr int NQB = N / BQ;        // 48
constexpr int SP_KH  = 0;
constexpr int SP_KL  = 16384;
constexpr int SP_VT  = 32768;      // [128 d][72 shorts] (144B rows)
constexpr int SP_PB  = 51200;
constexpr int SP_IDX = 59392;
constexpr int SPMF_SM = 59648;

// ws layout (bytes)
constexpr size_t CS_B   = 0;                        // [H][16][N] f32 = 3.1MB
constexpr size_t IDX_B  = 9437184;
constexpr size_t NSEL_B = IDX_B + (size_t)H*M*IDXCAP*4;
constexpr size_t KH_B   = NSEL_B + 1024;
constexpr size_t KL_B   = KH_B + 12582912;
}

typedef float f4v  __attribute__((ext_vector_type(4)));
typedef float f16v __attribute__((ext_vector_type(16)));
typedef short s8v  __attribute__((ext_vector_type(8)));

__device__ __forceinline__ unsigned short f2bf(float x) {
  unsigned u = __float_as_uint(x);
  unsigned r = u + 0x7FFFu + ((u >> 16) & 1u);
  return (unsigned short)(r >> 16);
}
__device__ __forceinline__ float bf2f(unsigned short b) {
  return __uint_as_float(((unsigned)b) << 16);
}

__device__ __forceinline__ void gload_lds16(const void* g, void* l) {
  __builtin_amdgcn_global_load_lds(
      (const __attribute__((address_space(1))) void*)g,
      (__attribute__((address_space(3))) void*)l, 16, 0, 0);
}

// P-fragment builders: cvt_pk pairs + permlane32_swap half exchange
#if __has_builtin(__builtin_amdgcn_permlane32_swap)
#define PLSWAP(a, b) do { \
  auto _r = __builtin_amdgcn_permlane32_swap(a, b, false, false); \
  a = _r[0]; b = _r[1]; \
} while (0)
#else
#define PLSWAP(a, b) \
  asm volatile("v_permlane32_swap_b32 %0, %1" : "+v"(a), "+v"(b))
#endif

#define MAKE_PFRAG(dst, a0,a1,a2,a3,a4,a5,a6,a7) do { \
  unsigned w01_, w23_, w45_, w67_; \
  asm("v_cvt_pk_bf16_f32 %0, %1, %2" : "=v"(w01_) : "v"(a0), "v"(a1)); \
  asm("v_cvt_pk_bf16_f32 %0, %1, %2" : "=v"(w23_) : "v"(a2), "v"(a3)); \
  asm("v_cvt_pk_bf16_f32 %0, %1, %2" : "=v"(w45_) : "v"(a4), "v"(a5)); \
  asm("v_cvt_pk_bf16_f32 %0, %1, %2" : "=v"(w67_) : "v"(a6), "v"(a7)); \
  PLSWAP(w01_, w45_); \
  PLSWAP(w23_, w67_); \
  union { unsigned u[4]; s8v s; } r_; \
  r_.u[0] = w01_; r_.u[1] = w23_; r_.u[2] = w45_; r_.u[3] = w67_; \
  dst = r_.s; \
} while (0)

// ------------------------------ threefry -----------------------------------
__device__ __forceinline__ void tf_round(uint32_t& x0, uint32_t& x1, int r) {
  x0 += x1; x1 = (x1 << r) | (x1 >> (32 - r)); x1 ^= x0;
}
__device__ __forceinline__ void tf2x32(uint32_t k0, uint32_t k1,
                                       uint32_t x0, uint32_t x1,
                                       uint32_t& y0, uint32_t& y1) {
  uint32_t k2 = k0 ^ k1 ^ 0x1BD11BDAu;
  x0 += k0; x1 += k1;
  tf_round(x0,x1,13); tf_round(x0,x1,15); tf_round(x0,x1,26); tf_round(x0,x1,6);
  x0 += k1; x1 += k2 + 1u;
  tf_round(x0,x1,17); tf_round(x0,x1,29); tf_round(x0,x1,16); tf_round(x0,x1,24);
  x0 += k2; x1 += k0 + 2u;
  tf_round(x0,x1,13); tf_round(x0,x1,15); tf_round(x0,x1,26); tf_round(x0,x1,6);
  x0 += k0; x1 += k1 + 3u;
  tf_round(x0,x1,17); tf_round(x0,x1,29); tf_round(x0,x1,16); tf_round(x0,x1,24);
  x0 += k1; x1 += k2 + 4u;
  tf_round(x0,x1,13); tf_round(x0,x1,15); tf_round(x0,x1,26); tf_round(x0,x1,6);
  x0 += k2; x1 += k0 + 5u;
  y0 = x0; y1 = x1;
}

__device__ __forceinline__ bool jax_rand_zero(uint32_t idx) {
  uint32_t hi, lo, r0, r1;
#if JAX_PARTITIONABLE
  uint32_t a0,a1,b0,b1;
  tf2x32(0u,42u, 0u,0u, a0,a1);
  tf2x32(0u,42u, 0u,1u, b0,b1);
  tf2x32(a0,a1, 0u, idx, r0,r1);  hi = r0 ^ r1;
  tf2x32(b0,b1, 0u, idx, r0,r1);  lo = r0 ^ r1;
#else
  uint32_t p0x,p0y,p1x,p1y;
  tf2x32(0u,42u, 0u,2u, p0x,p0y);
  tf2x32(0u,42u, 1u,3u, p1x,p1y);
  const uint32_t half = (uint32_t)((size_t)H*M*N) / 2u;
  uint32_t i = (idx < half) ? idx : (idx - half);
  uint32_t h0,h1,l0,l1;
  tf2x32(p0x, p1x, i, i + half, h0, h1);
  tf2x32(p0y, p1y, i, i + half, l0, l1);
  hi = (idx < half) ? h0 : h1;
  lo = (idx < half) ? l0 : l1;
#endif
  uint32_t off = ((hi % 100u) * 96u + (lo % 100u)) % 100u;
  return off == 0u;
}

// ----------------------- precompute: K -> Kh,Kl bf16 ------------------------
__global__ __launch_bounds__(256) void split_bf16_kernel(
    const float* __restrict__ K, unsigned short* __restrict__ Kh,
    unsigned short* __restrict__ Kl)
{
  size_t i = ((size_t)blockIdx.x * 256 + threadIdx.x) * 4;
  float4 v = *(const float4*)(K + i);
  unsigned short h0 = f2bf(v.x), h1 = f2bf(v.y), h2 = f2bf(v.z), h3 = f2bf(v.w);
  unsigned short l0 = f2bf(v.x - bf2f(h0)), l1 = f2bf(v.y - bf2f(h1));
  unsigned short l2 = f2bf(v.z - bf2f(h2)), l3 = f2bf(v.w - bf2f(h3));
  uint2 hu, lu;
  hu.x = (unsigned)h0 | ((unsigned)h1 << 16); hu.y = (unsigned)h2 | ((unsigned)h3 << 16);
  lu.x = (unsigned)l0 | ((unsigned)l1 << 16); lu.y = (unsigned)l2 | ((unsigned)l3 << 16);
  *(uint2*)(Kh + i) = hu;
  *(uint2*)(Kl + i) = lu;
}

// ----------------------- precompute: V -> Vt bf16 [H][Dh][N] ----------------
__global__ __launch_bounds__(256) void transpose_v_kernel(
    const float* __restrict__ Vm, unsigned short* __restrict__ Vt)
{
  __shared__ unsigned short tb[64][132];
  const int h  = blockIdx.x;
  const int cb = blockIdx.y;
  const int tid = threadIdx.x;
  const float* vg = Vm + (size_t)h*HEAD_STRIDE + (size_t)(cb*64)*Dh;
  #pragma unroll
  for (int it = 0; it < 8; ++it) {
    int f = tid + 256*it;
    int c = f >> 5, d0 = (f & 31)*4;
    float4 v = *(const float4*)(vg + c*Dh + d0);
    tb[c][d0+0] = f2bf(v.x); tb[c][d0+1] = f2bf(v.y);
    tb[c][d0+2] = f2bf(v.z); tb[c][d0+3] = f2bf(v.w);
  }
  __syncthreads();
  unsigned short* vt = Vt + (size_t)h*((size_t)Dh*N) + (size_t)(cb*64);
  #pragma unroll
  for (int it = 0; it < 4; ++it) {
    int f = tid + 256*it;
    int d = f >> 3, sl = f & 7;
    union { unsigned short us[8]; uint4 u; } o;
    #pragma unroll
    for (int i = 0; i < 8; ++i) o.us[i] = tb[sl*8 + i][d];
    *(uint4*)(vt + (size_t)d*N + sl*8) = o.u;
  }
}

// ---------- dense flash: 6 waves x 32q, 32x32x16 MFMA, swapped QK^T ---------
__global__ __launch_bounds__(384, 1) void dense_mfma4_kernel(
    const float* __restrict__ Qm, const unsigned short* __restrict__ Khg,
    const unsigned short* __restrict__ Klg, const unsigned short* __restrict__ Vtg,
    const float* __restrict__ PL, float* __restrict__ Out,
    float* __restrict__ csPart)
{
  extern __shared__ char smc[];
  float* CSR = (float*)(smc + D_CSR);

  // 256 blocks, XCD-chunked: 32 per XCD = 2 heads
  const int id  = blockIdx.x;
  const int wid = (id & 7) * 32 + (id >> 3);
  const int h   = wid >> 4;
  const int g   = wid & 15;           // colsum group == block
  const int q0  = g * 192;

  const int tid = threadIdx.x;
  const int wv  = tid >> 6;           // 0..5
  const int ln  = tid & 63;
  const int l31 = ln & 31;
  const int hi  = ln >> 5;
  const size_t hqk = (size_t)h * HEAD_STRIDE;

  const unsigned short* khg0 = Khg + hqk;
  const unsigned short* klg0 = Klg + hqk;
  const unsigned short* vtg0 = Vtg + (size_t)h*((size_t)Dh*N);

  // pre-computed per-lane staging source offsets (within a tile)
  // K chunks (ci 0..15): row = ci*4 + (ln>>4), slot = (ln&15) ^ (row&7)
  // VT chunks (cj 0..15): d = cj*8 + (ln>>3), slot = (ln&7) ^ (d&7)

  // ---- Q fragments: global -> reg, scale, hi/lo split (B-operand layout) ----
  s8v qh[8], ql[8];
  {
    const float* qrp = Qm + hqk + (size_t)(q0 + 32*wv + l31) * Dh;
    #pragma unroll
    for (int s = 0; s < 8; ++s) {
      int d0 = 16*s + 8*hi;
      float4 a = *(const float4*)(qrp + d0);
      float4 b = *(const float4*)(qrp + d0 + 4);
      float vals[8] = {a.x,a.y,a.z,a.w,b.x,b.y,b.z,b.w};
      union { unsigned short u[8]; s8v s; } hh, lo;
      #pragma unroll
      for (int j = 0; j < 8; ++j) {
        float x = vals[j] * SCALE;
        unsigned short hb = f2bf(x);
        hh.u[j] = hb;
        lo.u[j] = f2bf(x - bf2f(hb));
      }
      qh[s] = hh.s; ql[s] = lo.s;
    }
  }

  const float plr = PL[(size_t)h*N + q0 + 32*wv + l31];
  float mo = -1e30f, llv = 0.0f;
  f16v oacT[4];
  #pragma unroll
  for (int dt = 0; dt < 4; ++dt)
    #pragma unroll
    for (int r = 0; r < 16; ++r) oacT[dt][r] = 0.0f;

  const unsigned key = ((unsigned)(l31 & 7)) << 4;

  // ---- stage issuer: wave wv stages chunks 8wv..8wv+7 of tile kt into buf b
  auto issue_stage = [&](int b, int kt) {
    const unsigned short* khg = khg0 + (size_t)(kt*TK) * Dh;
    const unsigned short* klg = klg0 + (size_t)(kt*TK) * Dh;
    const unsigned short* vtg = vtg0 + (size_t)(kt*TK);
    char* bufb = smc + b*D_BUF;
    #pragma unroll
    for (int j = 0; j < 8; ++j) {
      int ci = 8*wv + j;                 // 0..47, wave-uniform
      char* ldst = bufb + ci*1024;
      const unsigned short* src;
      if (ci < 16) {
        int row = ci*4 + (ln >> 4);
        src = khg + row*Dh + (((ln & 15) ^ (row & 7)) << 3);
      } else if (ci < 32) {
        int row = (ci-16)*4 + (ln >> 4);
        src = klg + row*Dh + (((ln & 15) ^ (row & 7)) << 3);
      } else {
        int d = (ci-32)*8 + (ln >> 3);
        src = vtg + (size_t)d*N + (((ln & 7) ^ (d & 7)) << 3);
      }
      gload_lds16(src, ldst);
    }
  };

  // prologue: stage tile 0 into buf 0
  issue_stage(0, 0);
  asm volatile("s_waitcnt vmcnt(0)" ::: "memory");
  __syncthreads();

  for (int kt = 0; kt < NT; ++kt) {
    const int cur = kt & 1;
    if (kt + 1 < NT) issue_stage(cur ^ 1, kt + 1);   // async prefetch

    char* KH = smc + cur*D_BUF;
    char* KL = KH + 16384;
    char* VT = KH + 32768;

    // ---- QK^T (swapped): S^T[c][q], A = K rows c = 32ct+l31, B = Q^T ----
    f16v S0, S1;
    #pragma unroll
    for (int r = 0; r < 16; ++r) { S0[r] = 0.0f; S1[r] = 0.0f; }
    #pragma unroll
    for (int s = 0; s < 8; ++s) {
      unsigned doff = (unsigned)(s*32 + 16*hi);
      unsigned o0 = (unsigned)(l31*256) + (doff ^ key);
      unsigned o1 = o0 + 32*256;
      union { uint4 u; s8v v; } kh0, kl0, kh1, kl1;
      kh0.u = *(const uint4*)(KH + o0);
      kl0.u = *(const uint4*)(KL + o0);
      kh1.u = *(const uint4*)(KH + o1);
      kl1.u = *(const uint4*)(KL + o1);
      S0 = __builtin_amdgcn_mfma_f32_32x32x16_bf16(kh0.v, qh[s], S0, 0, 0, 0);
      S1 = __builtin_amdgcn_mfma_f32_32x32x16_bf16(kh1.v, qh[s], S1, 0, 0, 0);
      S0 = __builtin_amdgcn_mfma_f32_32x32x16_bf16(kh0.v, ql[s], S0, 0, 0, 0);
      S1 = __builtin_amdgcn_mfma_f32_32x32x16_bf16(kh1.v, ql[s], S1, 0, 0, 0);
      S0 = __builtin_amdgcn_mfma_f32_32x32x16_bf16(kl0.v, qh[s], S0, 0, 0, 0);
      S1 = __builtin_amdgcn_mfma_f32_32x32x16_bf16(kl1.v, qh[s], S1, 0, 0, 0);
    }

    // ---- online softmax: state is per-lane scalar (q = l31) ----
    float vmax = S0[0];
    #pragma unroll
    for (int r = 1; r < 16; ++r) vmax = fmaxf(vmax, S0[r]);
    #pragma unroll
    for (int r = 0; r < 16; ++r) vmax = fmaxf(vmax, S1[r]);
    vmax = fmaxf(vmax, __shfl_xor(vmax, 32));
    const float mn = fmaxf(mo, vmax);
    const float sc = __expf(mo - mn);
    const float wq = __expf(mn - plr);
    mo = mn;

    float p0[16], p1[16];
    float rs = 0.0f;
    #pragma unroll
    for (int r = 0; r < 16; ++r) { p0[r] = __expf(S0[r] - mn); rs += p0[r]; }
    #pragma unroll
    for (int r = 0; r < 16; ++r) { p1[r] = __expf(S1[r] - mn); rs += p1[r]; }
    rs += __shfl_xor(rs, 32);
    llv = llv * sc + rs;

    // ---- colsum: cs[c] = sum_q p*wq ; c = 32T + (i&3)+8*(i>>2)+4*hi ----
    #pragma unroll
    for (int i = 0; i < 16; ++i) {
      float cv = p0[i] * wq;
      cv += __shfl_xor(cv, 1);  cv += __shfl_xor(cv, 2);
      cv += __shfl_xor(cv, 4);  cv += __shfl_xor(cv, 8);
      cv += __shfl_xor(cv, 16);
      if ((ln & 31) == 0) CSR[wv*64 + (i&3) + 8*(i>>2) + 4*hi] = cv;
    }
    #pragma unroll
    for (int i = 0; i < 16; ++i) {
      float cv = p1[i] * wq;
      cv += __shfl_xor(cv, 1);  cv += __shfl_xor(cv, 2);
      cv += __shfl_xor(cv, 4);  cv += __shfl_xor(cv, 8);
      cv += __shfl_xor(cv, 16);
      if ((ln & 31) == 0) CSR[wv*64 + 32 + (i&3) + 8*(i>>2) + 4*hi] = cv;
    }

    // ---- rescale O^T accumulator (per-lane scalar) ----
    #pragma unroll
    for (int dt = 0; dt < 4; ++dt)
      #pragma unroll
      for (int r = 0; r < 16; ++r) oacT[dt][r] *= sc;

    // ---- P fragments via cvt_pk + permlane32_swap (no LDS) ----
    s8v pf0, pf1, pf2, pf3;
    MAKE_PFRAG(pf0, p0[0],p0[1],p0[2],p0[3],p0[4],p0[5],p0[6],p0[7]);
    MAKE_PFRAG(pf1, p0[8],p0[9],p0[10],p0[11],p0[12],p0[13],p0[14],p0[15]);
    MAKE_PFRAG(pf2, p1[0],p1[1],p1[2],p1[3],p1[4],p1[5],p1[6],p1[7]);
    MAKE_PFRAG(pf3, p1[8],p1[9],p1[10],p1[11],p1[12],p1[13],p1[14],p1[15]);

    // ---- PV: O^T[d][q] += V^T-frag x P-frag ----
    #pragma unroll
    for (int dt = 0; dt < 4; ++dt) {
      unsigned dbase = (unsigned)((32*dt + l31) * 128);
      union { uint4 u; s8v v; } v0, v1, v2, v3;
      v0.u = *(const uint4*)(VT + dbase + (((unsigned)(0*32 + 16*hi)) ^ key));
      v1.u = *(const uint4*)(VT + dbase + (((unsigned)(1*32 + 16*hi)) ^ key));
      v2.u = *(const uint4*)(VT + dbase + (((unsigned)(2*32 + 16*hi)) ^ key));
      v3.u = *(const uint4*)(VT + dbase + (((unsigned)(3*32 + 16*hi)) ^ key));
      oacT[dt] = __builtin_amdgcn_mfma_f32_32x32x16_bf16(v0.v, pf0, oacT[dt], 0, 0, 0);
      oacT[dt] = __builtin_amdgcn_mfma_f32_32x32x16_bf16(v1.v, pf1, oacT[dt], 0, 0, 0);
      oacT[dt] = __builtin_amdgcn_mfma_f32_32x32x16_bf16(v2.v, pf2, oacT[dt], 0, 0, 0);
      oacT[dt] = __builtin_amdgcn_mfma_f32_32x32x16_bf16(v3.v, pf3, oacT[dt], 0, 0, 0);
    }
    __syncthreads();   // #1: CSR writes visible; PV reads of buf[cur] done

    // ---- block colsum -> global (group g owned exclusively) ----
    if (tid < 64) {
      float c = ((CSR[tid] + CSR[64 + tid]) + (CSR[128 + tid] + CSR[192 + tid]))
              + (CSR[256 + tid] + CSR[320 + tid]);
      csPart[((size_t)(h*M + g))*N + kt*TK + tid] = c;
    }
    asm volatile("s_waitcnt vmcnt(0)" ::: "memory");  // prefetched buf landed
    __syncthreads();   // #2: CSR consumed; buf[cur^1] ready for next iter
  }

  // ---- epilogue: O^T regs -> LDS transpose -> coalesced global (2 passes) ----
  {
    const float inv = 1.0f / llv;
    #pragma unroll
    for (int dt = 0; dt < 4; ++dt)
      #pragma unroll
      for (int r = 0; r < 16; ++r) oacT[dt][r] *= inv;

    #pragma unroll
    for (int pass = 0; pass < 2; ++pass) {
      __syncthreads();
      if (wv >= 3*pass && wv < 3*pass + 3) {
        int qr = 32*(wv - 3*pass) + l31;              // 0..95
        unsigned qkey = ((unsigned)(qr & 7)) << 4;
        #pragma unroll
        for (int dt = 0; dt < 4; ++dt)
          #pragma unroll
          for (int G = 0; G < 4; ++G) {
            unsigned off = (unsigned)(qr*512) +
                (((unsigned)(dt*128 + G*32 + hi*16)) ^ qkey);
            float4 w;
            w.x = oacT[dt][4*G];   w.y = oacT[dt][4*G+1];
            w.z = oacT[dt][4*G+2]; w.w = oacT[dt][4*G+3];
            *(float4*)(smc + off) = w;
          }
      }
      __syncthreads();
      #pragma unroll
      for (int it = 0; it < 8; ++it) {
        int f = tid + 384*it;
        if (f < 3072) {
          int row = f >> 5, ds = f & 31;
          float4 v = *(const float4*)(smc + row*512 +
              (((unsigned)(ds*16)) ^ (((unsigned)(row & 7)) << 4)));
          *(float4*)(Out + hqk + (size_t)(q0 + 96*pass + row)*Dh + ds*4) = v;
        }
      }
    }
  }
}

// --------------------- sparse MFMA flash + out_cache (R5) -------------------
__global__ __launch_bounds__(256, 2) void sparse_mfma_kernel(
    const float* __restrict__ Qm, const unsigned short* __restrict__ Khg,
    const unsigned short* __restrict__ Klg, const float* __restrict__ Vm,
    const int* __restrict__ idxList, const int* __restrict__ nSel,
    float* __restrict__ Out)
{
  extern __shared__ char smc[];
  char* KH = smc + SP_KH;
  char* KL = smc + SP_KL;
  unsigned short* VTs = (unsigned short*)(smc + SP_VT);   // [128][72]
  char* PB = smc + SP_PB;
  int* idxs = (int*)(smc + SP_IDX);

  const int id  = blockIdx.x;
  const int wid = (id & 7) * 96 + (id >> 3);
  const int h   = wid / NQB;
  const int qb  = wid % NQB;
  const int gq  = qb / 3;
  const int q0  = qb * BQ;

  const int tid = threadIdx.x;
  const int wv  = tid >> 6;
  const int ln  = tid & 63;
  const int g   = ln >> 4;
  const int l15 = ln & 15;

  const size_t hqk = (size_t)h * HEAD_STRIDE;

  {
    const float* qg = Qm + hqk + (size_t)q0 * Dh;
    #pragma unroll
    for (int it = 0; it < 8; ++it) {
      int f = tid + 256*it;
      int row = f >> 5, d0 = (f & 31) * 4;
      float4 v = *(const float4*)(qg + row*Dh + d0);
      v.x *= SCALE; v.y *= SCALE; v.z *= SCALE; v.w *= SCALE;
      unsigned short h0 = f2bf(v.x), h1 = f2bf(v.y), h2 = f2bf(v.z), h3 = f2bf(v.w);
      unsigned short o0 = f2bf(v.x - bf2f(h0)), o1 = f2bf(v.y - bf2f(h1));
      unsigned short o2 = f2bf(v.z - bf2f(h2)), o3 = f2bf(v.w - bf2f(h3));
      unsigned off = (unsigned)(row*256) + (((unsigned)(d0*2)) ^ ((unsigned)(row&7) << 4));
      uint2 hu, lu;
      hu.x = (unsigned)h0 | ((unsigned)h1<<16); hu.y = (unsigned)h2 | ((unsigned)h3<<16);
      lu.x = (unsigned)o0 | ((unsigned)o1<<16); lu.y = (unsigned)o2 | ((unsigned)o3<<16);
      *(uint2*)(KH + off) = hu;
      *(uint2*)(KL + off) = lu;
    }
  }
  __syncthreads();
  s8v qh[4], qlo[4];
  {
    const int qrow = 16*wv + l15;
    const unsigned qswz = ((unsigned)(qrow & 7)) << 4;
    #pragma unroll
    for (int k0i = 0; k0i < 4; ++k0i) {
      unsigned off = (unsigned)(qrow*256) + (((unsigned)((k0i*4 + g)*16)) ^ qswz);
      union { uint4 u; s8v s; } a, b;
      a.u = *(const uint4*)(KH + off);
      b.u = *(const uint4*)(KL + off);
      qh[k0i] = a.s; qlo[k0i] = b.s;
    }
  }

  float mo[4], ll[4];
  #pragma unroll
  for (int r = 0; r < 4; ++r) { mo[r] = -1e30f; ll[r] = 0.0f; }
  f4v oacc[8];
  #pragma unroll
  for (int t = 0; t < 8; ++t) oacc[t] = (f4v){0.f, 0.f, 0.f, 0.f};

  const unsigned kswz = ((unsigned)(l15 & 7)) << 4;

  int nsel = nSel[h*M + gq];
  if (nsel > IDXCAP) nsel = IDXCAP;
  const int* il = idxList + ((size_t)h*M + gq) * IDXCAP;
  const int nt = (nsel + TK - 1) / TK;

  for (int t = 0; t < nt; ++t) {
    const int cnt = min(TK, nsel - t*TK);
    __syncthreads();
    if (tid < 64) idxs[tid] = (tid < cnt) ? il[t*TK + tid] : 0;
    __syncthreads();

    {
      const int row = tid & 63;
      const int c = idxs[row];
      const unsigned short* khr = Khg + hqk + (size_t)c * Dh;
      const unsigned short* klr = Klg + hqk + (size_t)c * Dh;
      const unsigned swz = ((unsigned)(row & 7)) << 4;
      #pragma unroll
      for (int j = 0; j < 4; ++j) {
        int chunk = (tid >> 6) + 4*j;
        unsigned off = (unsigned)(row*256) + (((unsigned)(chunk*16)) ^ swz);
        *(uint4*)(KH + off) = *(const uint4*)(khr + chunk*8);
        *(uint4*)(KL + off) = *(const uint4*)(klr + chunk*8);
      }
      const int q4 = tid & 15;
      const int seg = tid >> 4;
      int c4[4];
      #pragma unroll
      for (int j = 0; j < 4; ++j) c4[j] = idxs[4*q4 + j];
      union { float4 f4[2]; float f[8]; } col[4];
      #pragma unroll
      for (int j = 0; j < 4; ++j) {
        const float* vr = Vm + hqk + (size_t)c4[j]*Dh + 8*seg;
        col[j].f4[0] = *(const float4*)(vr);
        col[j].f4[1] = *(const float4*)(vr + 4);
      }
      #pragma unroll
      for (int dd = 0; dd < 8; ++dd) {
        unsigned short b0 = f2bf(col[0].f[dd]), b1 = f2bf(col[1].f[dd]);
        unsigned short b2 = f2bf(col[2].f[dd]), b3 = f2bf(col[3].f[dd]);
        uint2 pk;
        pk.x = (unsigned)b0 | ((unsigned)b1 << 16);
        pk.y = (unsigned)b2 | ((unsigned)b3 << 16);
        *(uint2*)((char*)VTs + (8*seg + dd)*144 + q4*8) = pk;
      }
    }
    __syncthreads();

    f4v S[4];
    #pragma unroll
    for (int u = 0; u < 4; ++u) S[u] = (f4v){0.f, 0.f, 0.f, 0.f};
    #pragma unroll
    for (int k0i = 0; k0i < 4; ++k0i) {
      #pragma unroll
      for (int u = 0; u < 4; ++u) {
        unsigned off = (unsigned)(u*4096 + l15*256) + (((unsigned)((k0i*4 + g)*16)) ^ kswz);
        union { uint4 u4; s8v s; } kh_, kl_;
        kh_.u4 = *(const uint4*)(KH + off);
        kl_.u4 = *(const uint4*)(KL + off);
        S[u] = __builtin_amdgcn_mfma_f32_16x16x32_bf16(qh[k0i], kh_.s, S[u], 0, 0, 0);
        S[u] = __builtin_amdgcn_mfma_f32_16x16x32_bf16(qh[k0i], kl_.s, S[u], 0, 0, 0);
        S[u] = __builtin_amdgcn_mfma_f32_16x16x32_bf16(qlo[k0i], kh_.s, S[u], 0, 0, 0);
      }
    }
    #pragma unroll
    for (int u = 0; u < 4; ++u)
      if (16*u + l15 >= cnt) S[u] = (f4v){-1e30f, -1e30f, -1e30f, -1e30f};

    float sc[4], p[4][4];
    #pragma unroll
    for (int r = 0; r < 4; ++r) {
      float v = fmaxf(fmaxf(S[0][r], S[1][r]), fmaxf(S[2][r], S[3][r]));
      v = fmaxf(v, __shfl_xor(v, 1)); v = fmaxf(v, __shfl_xor(v, 2));
      v = fmaxf(v, __shfl_xor(v, 4)); v = fmaxf(v, __shfl_xor(v, 8));
      float mn = fmaxf(mo[r], v);
      sc[r] = __expf(mo[r] - mn);
      mo[r] = mn;
    }
    #pragma unroll
    for (int r = 0; r < 4; ++r) {
      float rs = 0.f;
      #pragma unroll
      for (int u = 0; u < 4; ++u) { float pv = __expf(S[u][r] - mo[r]); p[u][r] = pv; rs += pv; }
      rs += __shfl_xor(rs, 1); rs += __shfl_xor(rs, 2);
      rs += __shfl_xor(rs, 4); rs += __shfl_xor(rs, 8);
      ll[r] = ll[r]*sc[r] + rs;
    }
    #pragma unroll
    for (int u = 0; u < 8; ++u) {
      f4v o = oacc[u];
      o[0] *= sc[0]; o[1] *= sc[1]; o[2] *= sc[2]; o[3] *= sc[3];
      oacc[u] = o;
    }
    #pragma unroll
    for (int r = 0; r < 4; ++r) {
      int qlr = 4*g + r;
      unsigned pkey = ((unsigned)((qlr >> 1) & 7)) << 4;
      char* rowp = PB + wv*2048 + qlr*128;
      #pragma unroll
      for (int u = 0; u < 4; ++u) {
        unsigned off = ((unsigned)(32*u + 2*l15)) ^ pkey;
        *(unsigned short*)(rowp + off) = f2bf(p[u][r]);
      }
    }
    __syncthreads();

    {
      const unsigned pkey = ((unsigned)((l15 >> 1) & 7)) << 4;
      const char* prow = PB + wv*2048 + l15*128;
      union { uint4 u4; s8v s; } pa0u, pa1u;
      pa0u.u4 = *(const uint4*)(prow + (((unsigned)(16*g)) ^ pkey));
      pa1u.u4 = *(const uint4*)(prow + (((unsigned)(64 + 16*g)) ^ pkey));
      s8v pa0 = pa0u.s, pa1 = pa1u.s;
      #pragma unroll
      for (int u = 0; u < 8; ++u) {
        const unsigned short* vrow = VTs + (16*u + l15)*72;
        union { uint4 u4; s8v s; } b0, b1;
        b0.u4 = *(const uint4*)(vrow + 8*g);
        b1.u4 = *(const uint4*)(vrow + 32 + 8*g);
        oacc[u] = __builtin_amdgcn_mfma_f32_16x16x32_bf16(pa0, b0.s, oacc[u], 0, 0, 0);
        oacc[u] = __builtin_amdgcn_mfma_f32_16x16x32_bf16(pa1, b1.s, oacc[u], 0, 0, 0);
      }
    }
  }

  {
    float inv[4];
    #pragma unroll
    for (int r = 0; r < 4; ++r) inv[r] = 1.0f / ll[r];
    #pragma unroll
    for (int t = 0; t < 8; ++t) {
      #pragma unroll
      for (int r = 0; r < 4; ++r) {
        int row = q0 + 16*wv + 4*g + r;
        size_t off = hqk + (size_t)row*Dh + 16*t + l15;
        Out[OUT_HALF + off] = Out[off] - oacc[t][r] * inv[r];
      }
    }
  }
}

// --------- selection: radix top-k + exact fp32 window + random mask ---------
__global__ __launch_bounds__(256) void select_kernel(
    const float* __restrict__ csPart, const int* __restrict__ topkPtr,
    const float* __restrict__ Qm, const float* __restrict__ Km,
    const float* __restrict__ PL,
    int* __restrict__ idxList, int* __restrict__ nSel)
{
  __shared__ uint32_t ubits[N];
  __shared__ int hist[256];
  __shared__ int cnt1[256], base1[256];
  __shared__ int sh_digit, sh_kk, sh_total, sh_A, sh_C;
  __shared__ float kcol[128];
  __shared__ float exacc[4];
  __shared__ int candIdx[CAND_MAX];
  __shared__ float candEx[CAND_MAX];
  __shared__ unsigned char candSel[CAND_MAX];
  __shared__ unsigned char selmap[N];

  const int bh = blockIdx.x;
  const int h = bh >> 4, g = bh & 15;
  const int tid = threadIdx.x;

  const float* p0 = csPart + (size_t)bh * N;
  for (int c = tid; c < N; c += 256) {
    ubits[c] = __float_as_uint(p0[c]);
    selmap[c] = 0;
  }
  __syncthreads();

  const int K = topkPtr[0];
  uint32_t prefix = 0; int kk = K;
  for (int pass = 0; pass < 4; ++pass) {
    const int shift = 24 - 8*pass;
    const uint32_t hm = (pass == 0) ? 0u : (0xFFFFFFFFu << (shift + 8));
    hist[tid] = 0;
    __syncthreads();
    for (int c = tid; c < N; c += 256) {
      uint32_t b = ubits[c];
      if ((b & hm) == (prefix & hm)) atomicAdd(&hist[(b >> shift) & 255], 1);
    }
    __syncthreads();
    if (tid == 0) {
      int cum = 0, d = 255;
      for (; d > 0; --d) { int hc = hist[d]; if (cum + hc >= kk) break; cum += hc; }
      sh_digit = d; sh_kk = kk - cum;
    }
    __syncthreads();
    prefix |= ((uint32_t)sh_digit) << shift;
    kk = sh_kk;
    __syncthreads();
  }
  const float thrv = __uint_as_float(prefix);
  const float hiv  = thrv * 1.001f;
  const float lov  = thrv * 0.999f;

  if (tid == 0) { sh_A = 0; sh_C = 0; }
  __syncthreads();
  const int CH = N / 256;
  const int c0 = tid * CH;
  int myIn = 0;
  for (int j = 0; j < CH; ++j) {
    float v = __uint_as_float(ubits[c0 + j]);
    if (v > hiv) myIn++;
    else if (v >= lov) {
      int slot = atomicAdd(&sh_C, 1);
      if (slot < CAND_MAX) candIdx[slot] = c0 + j;
    }
  }
  atomicAdd(&sh_A, myIn);
  __syncthreads();
  const int A = sh_A;
  const int C = min(sh_C, CAND_MAX);
  int need = K - A;
  if (need < 0) need = 0;
  if (need > C) need = C;

  const float* Qg = Qm + (size_t)h*HEAD_STRIDE + (size_t)(g*192)*Dh;
  const float* Kg = Km + (size_t)h*HEAD_STRIDE;
  const float  plq = (tid < 192) ? PL[(size_t)h*N + g*192 + tid] : 0.f;
  for (int ci = 0; ci < C; ++ci) {
    int c = candIdx[ci];
    if (tid < 128) kcol[tid] = Kg[(size_t)c*Dh + tid];
    __syncthreads();
    float e = 0.f;
    if (tid < 192) {
      const float* qr = Qg + (size_t)tid*Dh;
      float acc = 0.f;
      #pragma unroll
      for (int d4 = 0; d4 < 32; ++d4) {
        float4 qv = *(const float4*)(qr + d4*4);
        acc += qv.x*kcol[d4*4] + qv.y*kcol[d4*4+1] + qv.z*kcol[d4*4+2] + qv.w*kcol[d4*4+3];
      }
      e = expf(acc*SCALE - plq);
    }
    #pragma unroll
    for (int s = 1; s < 64; s <<= 1) e += __shfl_xor(e, s);
    if ((tid & 63) == 0) exacc[tid >> 6] = e;
    __syncthreads();
    if (tid == 0) candEx[ci] = (exacc[0] + exacc[1]) + (exacc[2] + exacc[3]);
    __syncthreads();
  }

  if (tid < C) {
    float ei = candEx[tid]; int ii = candIdx[tid];
    int rank = 0;
    for (int j = 0; j < C; ++j) {
      float ej = candEx[j];
      if (ej > ei || (ej == ei && candIdx[j] < ii)) ++rank;
    }
    candSel[tid] = (rank < need) ? 1 : 0;
  }
  __syncthreads();
  if (tid < C && candSel[tid]) selmap[candIdx[tid]] = 1;
  __syncthreads();

  bool fl[12]; int selc = 0;
  for (int j = 0; j < CH; ++j) {
    int c = c0 + j;
    float v = __uint_as_float(ubits[c]);
    bool s = (v > hiv) || (selmap[c] != 0);
    if (!s) s = jax_rand_zero((uint32_t)bh * (uint32_t)N + (uint32_t)c);
    fl[j] = s; selc += s ? 1 : 0;
  }
  cnt1[tid] = selc;
  __syncthreads();
  if (tid == 0) { int run = 0; for (int t = 0; t < 256; ++t) { base1[t] = run; run += cnt1[t]; } sh_total = run; }
  __syncthreads();
  int w = base1[tid];
  int* il = idxList + (size_t)bh * IDXCAP;
  for (int j = 0; j < CH; ++j) if (fl[j]) { if (w < IDXCAP) il[w] = c0 + j; ++w; }
  if (tid == 0) nSel[bh] = (sh_total < IDXCAP) ? sh_total : IDXCAP;
}

// ------------------------------- launch -------------------------------------
extern "C" void kernel_launch(void* const* d_in, const int* in_sizes, int n_in,
                              void* d_out, int out_size, void* d_ws, size_t ws_size,
                              hipStream_t stream) {
  const float* q  = (const float*)d_in[0];
  const float* k  = (const float*)d_in[1];
  const float* v  = (const float*)d_in[2];
  const float* pl = (const float*)d_in[3];
  const int* topk = (const int*)d_in[4];
  float* out = (float*)d_out;
  char* ws   = (char*)d_ws;

  float* csPart = (float*)(ws + CS_B);
  int*   idxL   = (int*)(ws + IDX_B);
  int*   nSel   = (int*)(ws + NSEL_B);
  unsigned short* Kh = (unsigned short*)(ws + KH_B);
  unsigned short* Kl = (unsigned short*)(ws + KL_B);
  unsigned short* Vt = (unsigned short*)(out + OUT_HALF);  // scratch; only dense reads

  (void)hipFuncSetAttribute((const void*)dense_mfma4_kernel,
      hipFuncAttributeMaxDynamicSharedMemorySize, DENSE_SM);
  (void)hipFuncSetAttribute((const void*)sparse_mfma_kernel,
      hipFuncAttributeMaxDynamicSharedMemorySize, SPMF_SM);

  split_bf16_kernel<<<6144, 256, 0, stream>>>(k, Kh, Kl);
  transpose_v_kernel<<<dim3(H, N/64), 256, 0, stream>>>(v, Vt);
  dense_mfma4_kernel<<<256, 384, DENSE_SM, stream>>>(q, Kh, Kl, Vt, pl, out, csPart);
  select_kernel<<<dim3(H * M), 256, 0, stream>>>(csPart, topk, q, k, pl, idxL, nSel);
  sparse_mfma_kernel<<<768, 256, SPMF_SM, stream>>>(q, Kh, Kl, v, idxL, nSel, out);
}